// Round 6
// baseline (2051.463 us; speedup 1.0000x reference)
//
#include <hip/hip_runtime.h>
#include <math.h>

// Problem constants (fixed by the reference)
#define BATCH 2
#define T_LEN 2048
#define D_DIM 1024
#define KSEL  15
#define HIDN  64

__device__ __forceinline__ float geluf(float x) {
  return 0.5f * x * (1.0f + erff(x * 0.70710678118654752440f));
}

// ---------------------------------------------------------------------------
// f32 GEMM, 128x128 tile, BK=16, 256 threads, 8x8 per thread. Smooth path only
// (final V @ Wo).
// ---------------------------------------------------------------------------
__global__ void __launch_bounds__(256) gemm128(const float* __restrict__ A,
                                               const float* __restrict__ B,
                                               float* __restrict__ C,
                                               int M, int N, int K, float alpha)
{
  const int m0 = blockIdx.y << 7, n0 = blockIdx.x << 7;
  const int tid = threadIdx.x;
  const int tx = tid & 15, ty = tid >> 4;

  __shared__ float As[16][128];
  __shared__ float Bs[16][132];

  float acc[8][8];
#pragma unroll
  for (int i = 0; i < 8; ++i)
#pragma unroll
    for (int j = 0; j < 8; ++j) acc[i][j] = 0.f;

  for (int k0 = 0; k0 < K; k0 += 16) {
#pragma unroll
    for (int rep = 0; rep < 2; ++rep) {
      int q = tid + (rep << 8);
      int m = q >> 2, kq = (q & 3) << 2;
      float4 a = *(const float4*)(A + (size_t)(m0 + m) * K + k0 + kq);
      As[kq + 0][m] = a.x; As[kq + 1][m] = a.y; As[kq + 2][m] = a.z; As[kq + 3][m] = a.w;
    }
#pragma unroll
    for (int rep = 0; rep < 2; ++rep) {
      int q = tid + (rep << 8);
      int kk = q >> 5, n4 = q & 31;
      *(float4*)&Bs[kk][n4 << 2] =
          *(const float4*)(B + (size_t)(k0 + kk) * N + n0 + (n4 << 2));
    }
    __syncthreads();
#pragma unroll
    for (int kk = 0; kk < 16; ++kk) {
      float4 a0 = *(const float4*)&As[kk][ty << 3];
      float4 a1 = *(const float4*)&As[kk][(ty << 3) + 4];
      float4 b0 = *(const float4*)&Bs[kk][tx << 3];
      float4 b1 = *(const float4*)&Bs[kk][(tx << 3) + 4];
      float av[8] = {a0.x, a0.y, a0.z, a0.w, a1.x, a1.y, a1.z, a1.w};
      float bv[8] = {b0.x, b0.y, b0.z, b0.w, b1.x, b1.y, b1.z, b1.w};
#pragma unroll
      for (int i = 0; i < 8; ++i)
#pragma unroll
        for (int j = 0; j < 8; ++j)
          acc[i][j] = fmaf(av[i], bv[j], acc[i][j]);
    }
    __syncthreads();
  }
#pragma unroll
  for (int i = 0; i < 8; ++i) {
    size_t coff = (size_t)(m0 + (ty << 3) + i) * N + n0 + (tx << 3);
    float4 o0 = make_float4(acc[i][0] * alpha, acc[i][1] * alpha, acc[i][2] * alpha, acc[i][3] * alpha);
    float4 o1 = make_float4(acc[i][4] * alpha, acc[i][5] * alpha, acc[i][6] * alpha, acc[i][7] * alpha);
    *(float4*)(C + coff) = o0;
    *(float4*)(C + coff + 4) = o1;
  }
}

// ---------------------------------------------------------------------------
// f64-ACCUMULATE GEMM v4 (f32 in / f32 out). BM=64 x BN=128 tile, BK=16,
// 256 threads, 4x8 f64 per thread, STRIDED ownership (rows ty+16i, cols
// tx+16j) -> conflict-free inner-loop reads. LDS double-buffered with
// register prefetch (one barrier per K-step). z-fused: blockIdx.z selects
// {B=Ba or Bb} + per-z A/B/C offsets, so both x@W GEMMs (or both batches
// of S) run in ONE launch -> ~3-4 blocks/CU instead of 1.
// Accumulation order per output: K-tiles ascending, kk ascending, fma
// sequential -> BIT-IDENTICAL to r3-r5 (selection semantics locked).
// C[m][n] = (float)(alpha * sum_k A[m][k] * (BT ? B[n][k] : B[k][n]))
// ---------------------------------------------------------------------------
template<bool BT, bool CAUSAL>
__global__ void __launch_bounds__(256) gemm64s(
    const float* __restrict__ A, const float* __restrict__ Ba,
    const float* __restrict__ Bb, float* __restrict__ C,
    int N, int K, long sA, long sB, long sC, double alpha)
{
  const int m0 = blockIdx.y << 6;   // BM=64
  const int n0 = blockIdx.x << 7;   // BN=128
  if (CAUSAL && n0 > m0 + 63) return;
  const int z = blockIdx.z;
  A += (size_t)z * sA;
  const float* B = (z ? Bb : Ba) + (size_t)z * sB;
  C += (size_t)z * sC;

  const int tid = threadIdx.x;
  const int tx = tid & 15, ty = tid >> 4;

  __shared__ double As[2][16][66];    // [buf][k][m], pad 66
  __shared__ double Bs[2][16][130];   // [buf][k][n], pad 130

  double acc[4][8];
#pragma unroll
  for (int i = 0; i < 4; ++i)
#pragma unroll
    for (int j = 0; j < 8; ++j) acc[i][j] = 0.0;

  // staging ownership
  const int am = tid >> 2, akq = (tid & 3) << 2;   // A: row am, k akq..akq+3
  const int bk = tid >> 4, bn = (tid & 15) << 3;   // B !BT: k-row bk, cols bn..bn+7
  const int tn = tid >> 1, tkq = (tid & 1) << 3;   // B  BT: n-row tn, k tkq..tkq+7

  float4 ra, rb0, rb1;

  // prologue: load k0=0, write buf 0
  ra = *(const float4*)(A + (size_t)(m0 + am) * K + akq);
  if (!BT) {
    const float* bp = B + (size_t)bk * N + n0 + bn;
    rb0 = *(const float4*)(bp);
    rb1 = *(const float4*)(bp + 4);
  } else {
    const float* bp = B + (size_t)(n0 + tn) * K + tkq;
    rb0 = *(const float4*)(bp);
    rb1 = *(const float4*)(bp + 4);
  }
  {
    As[0][akq + 0][am] = (double)ra.x; As[0][akq + 1][am] = (double)ra.y;
    As[0][akq + 2][am] = (double)ra.z; As[0][akq + 3][am] = (double)ra.w;
    if (!BT) {
      Bs[0][bk][bn + 0] = (double)rb0.x; Bs[0][bk][bn + 1] = (double)rb0.y;
      Bs[0][bk][bn + 2] = (double)rb0.z; Bs[0][bk][bn + 3] = (double)rb0.w;
      Bs[0][bk][bn + 4] = (double)rb1.x; Bs[0][bk][bn + 5] = (double)rb1.y;
      Bs[0][bk][bn + 6] = (double)rb1.z; Bs[0][bk][bn + 7] = (double)rb1.w;
    } else {
      Bs[0][tkq + 0][tn] = (double)rb0.x; Bs[0][tkq + 1][tn] = (double)rb0.y;
      Bs[0][tkq + 2][tn] = (double)rb0.z; Bs[0][tkq + 3][tn] = (double)rb0.w;
      Bs[0][tkq + 4][tn] = (double)rb1.x; Bs[0][tkq + 5][tn] = (double)rb1.y;
      Bs[0][tkq + 6][tn] = (double)rb1.z; Bs[0][tkq + 7][tn] = (double)rb1.w;
    }
  }
  __syncthreads();

  int buf = 0;
  for (int k0 = 0; k0 < K; k0 += 16) {
    const bool more = (k0 + 16) < K;
    if (more) {
      const int kn = k0 + 16;
      ra = *(const float4*)(A + (size_t)(m0 + am) * K + kn + akq);
      if (!BT) {
        const float* bp = B + (size_t)(kn + bk) * N + n0 + bn;
        rb0 = *(const float4*)(bp);
        rb1 = *(const float4*)(bp + 4);
      } else {
        const float* bp = B + (size_t)(n0 + tn) * K + kn + tkq;
        rb0 = *(const float4*)(bp);
        rb1 = *(const float4*)(bp + 4);
      }
    }
    // compute current buffer
#pragma unroll
    for (int kk = 0; kk < 16; ++kk) {
      double av[4], bv[8];
#pragma unroll
      for (int i = 0; i < 4; ++i) av[i] = As[buf][kk][ty + (i << 4)];
#pragma unroll
      for (int j = 0; j < 8; ++j) bv[j] = Bs[buf][kk][tx + (j << 4)];
#pragma unroll
      for (int i = 0; i < 4; ++i)
#pragma unroll
        for (int j = 0; j < 8; ++j)
          acc[i][j] = fma(av[i], bv[j], acc[i][j]);
    }
    if (more) {
      const int nb = buf ^ 1;
      As[nb][akq + 0][am] = (double)ra.x; As[nb][akq + 1][am] = (double)ra.y;
      As[nb][akq + 2][am] = (double)ra.z; As[nb][akq + 3][am] = (double)ra.w;
      if (!BT) {
        Bs[nb][bk][bn + 0] = (double)rb0.x; Bs[nb][bk][bn + 1] = (double)rb0.y;
        Bs[nb][bk][bn + 2] = (double)rb0.z; Bs[nb][bk][bn + 3] = (double)rb0.w;
        Bs[nb][bk][bn + 4] = (double)rb1.x; Bs[nb][bk][bn + 5] = (double)rb1.y;
        Bs[nb][bk][bn + 6] = (double)rb1.z; Bs[nb][bk][bn + 7] = (double)rb1.w;
      } else {
        Bs[nb][tkq + 0][tn] = (double)rb0.x; Bs[nb][tkq + 1][tn] = (double)rb0.y;
        Bs[nb][tkq + 2][tn] = (double)rb0.z; Bs[nb][tkq + 3][tn] = (double)rb0.w;
        Bs[nb][tkq + 4][tn] = (double)rb1.x; Bs[nb][tkq + 5][tn] = (double)rb1.y;
        Bs[nb][tkq + 6][tn] = (double)rb1.z; Bs[nb][tkq + 7][tn] = (double)rb1.w;
      }
    }
    __syncthreads();
    buf ^= 1;
  }
#pragma unroll
  for (int i = 0; i < 4; ++i) {
    size_t rbase = (size_t)(m0 + ty + (i << 4)) * N + n0 + tx;
#pragma unroll
    for (int j = 0; j < 8; ++j)
      C[rbase + (j << 4)] = (float)(acc[i][j] * alpha);
  }
}

// ---------------------------------------------------------------------------
// RoPE in place + row L2 norms. Replicates the reference's f32 trig EXACTLY
// (see r3 notes). DO NOT change — this is what makes top-15 selection match.
// ---------------------------------------------------------------------------
__global__ void __launch_bounds__(256) rope_norm_kernel(float* __restrict__ bI,
                                                        float* __restrict__ bP,
                                                        float* __restrict__ nI,
                                                        float* __restrict__ nP)
{
  const int row = blockIdx.x;
  const int t = row & (T_LEN - 1);
  const int tid = threadIdx.x;
  __shared__ double redI[4], redP[4];
  double ssI = 0.0, ssP = 0.0;
  const size_t off = (size_t)row * D_DIM;
  for (int j = tid; j < 512; j += 256) {
    double e = (double)j * (1.0 / 512.0);
    float pf = (float)pow(10000.0, e);
    float invf = 1.0f / pf;
    float angf = (float)t * invf;
    double s64, c64;
    sincos((double)angf, &s64, &c64);
    float c = (float)c64, s = (float)s64;

    float a1 = bI[off + j], a2 = bI[off + 512 + j];
    float o1 = __fsub_rn(__fmul_rn(a1, c), __fmul_rn(a2, s));
    float o2 = __fadd_rn(__fmul_rn(a1, s), __fmul_rn(a2, c));
    bI[off + j] = o1; bI[off + 512 + j] = o2;
    ssI += (double)o1 * o1 + (double)o2 * o2;

    float p1 = bP[off + j], p2 = bP[off + 512 + j];
    float q1 = __fsub_rn(__fmul_rn(p1, c), __fmul_rn(p2, s));
    float q2 = __fadd_rn(__fmul_rn(p1, s), __fmul_rn(p2, c));
    bP[off + j] = q1; bP[off + 512 + j] = q2;
    ssP += (double)q1 * q1 + (double)q2 * q2;
  }
#pragma unroll
  for (int o = 32; o >= 1; o >>= 1) { ssI += __shfl_xor(ssI, o); ssP += __shfl_xor(ssP, o); }
  if ((tid & 63) == 0) { redI[tid >> 6] = ssI; redP[tid >> 6] = ssP; }
  __syncthreads();
  if (tid == 0) {
    nI[row] = fmaxf((float)sqrt(redI[0] + redI[1] + redI[2] + redI[3]), 1e-12f);
    nP[row] = fmaxf((float)sqrt(redP[0] + redP[1] + redP[2] + redP[3]), 1e-12f);
  }
}

// ---------------------------------------------------------------------------
// palette (D x 256) -> palT (256 x D)
// ---------------------------------------------------------------------------
__global__ void transpose_pal(const float* __restrict__ pal, float* __restrict__ palT)
{
  int c = blockIdx.x;
  int d = blockIdx.y * 256 + threadIdx.x;
  palT[(size_t)c * D_DIM + d] = pal[(size_t)d * 256 + c];
}

// ---------------------------------------------------------------------------
// Top-15 per causal row. One wave per row. Descending; ties -> lower index.
// ---------------------------------------------------------------------------
__global__ void __launch_bounds__(256) topk_kernel(const float* __restrict__ S,
                                                   int* __restrict__ idx, int b)
{
  const int wave = threadIdx.x >> 6, lane = threadIdx.x & 63;
  const int t = blockIdx.x * 4 + wave;
  const float* rowp = S + (size_t)t * T_LEN;
  float v[32];
#pragma unroll
  for (int i = 0; i < 32; ++i) {
    int s = lane + (i << 6);
    v[i] = (s <= t) ? rowp[s] : -INFINITY;
  }
  float pv = INFINITY; int pidx = -1;
  int* outp = idx + ((size_t)b * T_LEN + t) * 16;
  for (int k = 0; k < KSEL; ++k) {
    float bv = -INFINITY; int bi = 0x7fffffff;
#pragma unroll
    for (int i = 0; i < 32; ++i) {
      int s = lane + (i << 6);
      float vv = v[i];
      bool elig = (vv < pv) || (vv == pv && s > pidx);
      if (elig && vv > bv) { bv = vv; bi = s; }
    }
#pragma unroll
    for (int o = 32; o >= 1; o >>= 1) {
      float ov = __shfl_xor(bv, o);
      int oi = __shfl_xor(bi, o);
      if (ov > bv || (ov == bv && oi < bi)) { bv = ov; bi = oi; }
    }
    pv = bv; pidx = bi;
    if (lane == 0) outp[k] = (bi == 0x7fffffff || bv == -INFINITY) ? 0 : bi;
  }
}

// ---------------------------------------------------------------------------
// Per-(b,t): gather + normalized gram + rel features + MLP + heads + softmax
// + bilinear palette blend -> V[b,t,:].
// ---------------------------------------------------------------------------
__global__ void __launch_bounds__(256) relmlp_kernel(
    const float* __restrict__ I, const float* __restrict__ P,
    const float* __restrict__ nI, const float* __restrict__ nP,
    const int* __restrict__ topk,
    const float* __restrict__ W1, const float* __restrict__ b1,
    const float* __restrict__ W2, const float* __restrict__ b2,
    const float* __restrict__ Wc, const float* __restrict__ bc,
    const float* __restrict__ Wm, const float* __restrict__ bm,
    const float* __restrict__ palT, float* __restrict__ V)
{
  const int row = blockIdx.x;
  const int t = row & (T_LEN - 1);
  const int base = row & ~(T_LEN - 1);
  const int nk = (t + 1 < KSEL) ? (t + 1) : KSEL;
  const int tid = threadIdx.x;

  __shared__ float vecS[16][516];
  __shared__ float gS[16][16];
  __shared__ float relS[KSEL][17];
  __shared__ float h1S[KSEL][HIDN];
  __shared__ float h2S[KSEL][HIDN];
  __shared__ float nrmS[16];
  __shared__ int   sidxS[16];
  __shared__ float mixS[KSEL], wS[KSEL], zxS[KSEL], zyS[KSEL];
  __shared__ float coefS[4 * KSEL];
  __shared__ int   cellS[4 * KSEL];

  if (tid < 16) {
    int s = t;
    if (tid >= 1) s = (tid <= nk) ? topk[(size_t)row * 16 + (tid - 1)] : 0;
    sidxS[tid] = s;
    nrmS[tid] = (tid == 0) ? nI[row] : nP[base + s];
  }
  __syncthreads();

  const int r = tid >> 4, c0 = tid & 15;
  const float* srcrow = (r == 0) ? (I + (size_t)row * D_DIM)
                                 : (P + ((size_t)base + sidxS[r]) * D_DIM);

  int pi = 0, pj = 0;
  {
    int p = tid;
    if (p < 136) {
      int i = 0;
      while (p >= 16 - i) { p -= 16 - i; ++i; }
      pi = i; pj = i + p;
    }
  }
  const bool pairOn = (tid < 136) && (pi <= nk) && (pj <= nk);
  float4 acc4 = make_float4(0.f, 0.f, 0.f, 0.f);

  for (int half = 0; half < 2; ++half) {
    if (half) __syncthreads();
    if (r <= nk) {
#pragma unroll
      for (int rep = 0; rep < 8; ++rep) {
        int q = c0 + 16 * rep;
        float4 v4 = *(const float4*)(srcrow + half * 512 + (q << 2));
        *(float4*)&vecS[r][q << 2] = v4;
      }
    }
    __syncthreads();
    if (pairOn) {
      const float4* va = (const float4*)&vecS[pi][0];
      const float4* vb = (const float4*)&vecS[pj][0];
#pragma unroll 4
      for (int q = 0; q < 128; ++q) {
        float4 a4 = va[q], b4 = vb[q];
        acc4.x = fmaf(a4.x, b4.x, acc4.x);
        acc4.y = fmaf(a4.y, b4.y, acc4.y);
        acc4.z = fmaf(a4.z, b4.z, acc4.z);
        acc4.w = fmaf(a4.w, b4.w, acc4.w);
      }
    }
  }
  if (tid < 136) {
    float g = 0.f;
    if (pairOn) {
      float acc = (acc4.x + acc4.y) + (acc4.z + acc4.w);
      g = acc / (nrmS[pi] * nrmS[pj]);
      g = fminf(fmaxf(g, -1.f), 1.f);
    }
    gS[pi][pj] = g;
    gS[pj][pi] = g;
  }
  __syncthreads();

  if (tid < KSEL * 17) {
    int k = tid / 17, f = tid % 17;
    float v = 0.f;
    if (k < nk) {
      if (f < KSEL)        v = (f < nk) ? gS[k + 1][f + 1] : 0.f;
      else if (f == KSEL)  v = gS[0][k + 1];
      else                 v = (float)(t - sidxS[k + 1]) * (1.0f / (float)T_LEN);
    }
    relS[k][f] = v;
  }
  __syncthreads();

  for (int o = tid; o < KSEL * HIDN; o += 256) {
    int k = o >> 6, m = o & 63;
    float a = b1[m];
#pragma unroll
    for (int f = 0; f < 17; ++f) a = fmaf(relS[k][f], W1[f * HIDN + m], a);
    h1S[k][m] = geluf(a);
  }
  __syncthreads();
  for (int o = tid; o < KSEL * HIDN; o += 256) {
    int k = o >> 6, m = o & 63;
    float a = b2[m];
#pragma unroll 8
    for (int n = 0; n < HIDN; ++n) a = fmaf(h1S[k][n], W2[n * HIDN + m], a);
    h2S[k][m] = geluf(a);
  }
  __syncthreads();
  if (tid < KSEL) {
    float a0 = 0.f, a1 = 0.f, am = 0.f;
#pragma unroll 8
    for (int n = 0; n < HIDN; ++n) {
      float h = h2S[tid][n];
      a0 = fmaf(h, Wc[n * 2 + 0], a0);
      a1 = fmaf(h, Wc[n * 2 + 1], a1);
      am = fmaf(h, Wm[n], am);
    }
    zxS[tid] = tanhf(a0 + bc[0]);
    zyS[tid] = tanhf(a1 + bc[1]);
    mixS[tid] = am + bm[0];
  }
  __syncthreads();
  if (tid == 0) {
    float mx = -INFINITY;
    for (int k = 0; k < nk; ++k) mx = fmaxf(mx, mixS[k]);
    float ssum = 0.f;
    for (int k = 0; k < nk; ++k) { float e = expf(mixS[k] - mx); wS[k] = e; ssum += e; }
    float inv = 1.f / ssum;
    for (int k = 0; k < nk; ++k) wS[k] *= inv;
  }
  __syncthreads();
  if (tid < KSEL) {
    int k = tid;
    if (k < nk) {
      float w = wS[k];
      float fx = fminf(fmaxf((zxS[k] + 1.f) * 0.5f * 15.f, 0.f), 15.f);
      float fy = fminf(fmaxf((zyS[k] + 1.f) * 0.5f * 15.f, 0.f), 15.f);
      int x0 = (int)floorf(fx); int x1i = (x0 + 1 < 15) ? x0 + 1 : 15;
      int y0 = (int)floorf(fy); int y1i = (y0 + 1 < 15) ? y0 + 1 : 15;
      float wx = fx - (float)x0, wy = fy - (float)y0;
      cellS[k * 4 + 0] = y0 * 16 + x0;   coefS[k * 4 + 0] = w * (1.f - wy) * (1.f - wx);
      cellS[k * 4 + 1] = y0 * 16 + x1i;  coefS[k * 4 + 1] = w * (1.f - wy) * wx;
      cellS[k * 4 + 2] = y1i * 16 + x0;  coefS[k * 4 + 2] = w * wy * (1.f - wx);
      cellS[k * 4 + 3] = y1i * 16 + x1i; coefS[k * 4 + 3] = w * wy * wx;
    } else {
      cellS[k * 4 + 0] = cellS[k * 4 + 1] = cellS[k * 4 + 2] = cellS[k * 4 + 3] = 0;
      coefS[k * 4 + 0] = coefS[k * 4 + 1] = coefS[k * 4 + 2] = coefS[k * 4 + 3] = 0.f;
    }
  }
  __syncthreads();
  const int nj = 4 * nk;
  for (int d = tid; d < D_DIM; d += 256) {
    float a = 0.f;
    for (int j = 0; j < nj; ++j)
      a = fmaf(coefS[j], palT[(size_t)cellS[j] * D_DIM + d], a);
    V[(size_t)row * D_DIM + d] = a;
  }
}

// ---------------------------------------------------------------------------
// Host launcher. Workspace (floats, ~65.3 MiB):
//   palT | I | P | S(2 batches, 32MB; V aliases S after topk) | norms | idx
// ---------------------------------------------------------------------------
extern "C" void kernel_launch(void* const* d_in, const int* in_sizes, int n_in,
                              void* d_out, int out_size, void* d_ws, size_t ws_size,
                              hipStream_t stream)
{
  (void)in_sizes; (void)n_in; (void)out_size; (void)ws_size;
  const float* x   = (const float*)d_in[0];
  const float* Wi  = (const float*)d_in[1];
  const float* Wp  = (const float*)d_in[2];
  const float* pal = (const float*)d_in[3];
  const float* W1  = (const float*)d_in[4];
  const float* b1  = (const float*)d_in[5];
  const float* W2  = (const float*)d_in[6];
  const float* b2  = (const float*)d_in[7];
  const float* Wc  = (const float*)d_in[8];
  const float* bc  = (const float*)d_in[9];
  const float* Wm  = (const float*)d_in[10];
  const float* bm  = (const float*)d_in[11];
  const float* Wo  = (const float*)d_in[12];
  float* out = (float*)d_out;

  float* w = (float*)d_ws;
  float* palT = w;  w += (size_t)256 * D_DIM;
  float* I    = w;  w += (size_t)BATCH * T_LEN * D_DIM;   // P follows contiguously
  float* P    = w;  w += (size_t)BATCH * T_LEN * D_DIM;
  float* Sb   = w;  w += (size_t)BATCH * T_LEN * T_LEN;   // 2 batches of S
  float* Vb   = Sb;                                        // V aliases S (used after topk)
  float* nIb  = w;  w += (size_t)BATCH * T_LEN;
  float* nPb  = w;  w += (size_t)BATCH * T_LEN;
  int*   idx  = (int*)w;

  const int MROWS = BATCH * T_LEN;  // 4096

  transpose_pal<<<dim3(256, 4), 256, 0, stream>>>(pal, palT);

  // I = x@Wi (z=0), P = x@Wp (z=1) — one fused launch, shared A.
  gemm64s<false, false><<<dim3(D_DIM / 128, MROWS / 64, 2), 256, 0, stream>>>(
      x, Wi, Wp, I, D_DIM, D_DIM,
      0L, 0L, (long)MROWS * D_DIM, 1.0);

  rope_norm_kernel<<<MROWS, 256, 0, stream>>>(I, P, nIb, nPb);

  // S[b] = (I_b @ P_b^T) * D^-0.5, both batches in one causal launch.
  gemm64s<true, true><<<dim3(T_LEN / 128, T_LEN / 64, 2), 256, 0, stream>>>(
      I, P, P, Sb, T_LEN, D_DIM,
      (long)T_LEN * D_DIM, (long)T_LEN * D_DIM, (long)T_LEN * T_LEN, 0.03125);

  for (int b = 0; b < BATCH; ++b)
    topk_kernel<<<T_LEN / 4, 256, 0, stream>>>(Sb + (size_t)b * T_LEN * T_LEN, idx, b);

  relmlp_kernel<<<MROWS, 256, 0, stream>>>(I, P, nIb, nPb, idx,
                                           W1, b1, W2, b2, Wc, bc, Wm, bm,
                                           palT, Vb);

  gemm128<<<dim3(D_DIM / 128, MROWS / 128), 256, 0, stream>>>(
      Vb, Wo, out, MROWS, D_DIM, D_DIM, 1.0f);
}

// Round 8
// 934.478 us; speedup vs baseline: 2.1953x; 2.1953x over previous
//
#include <hip/hip_runtime.h>
#include <math.h>

// Problem constants (fixed by the reference)
#define BATCH 2
#define T_LEN 2048
#define D_DIM 1024
#define KSEL  15
#define HIDN  64

typedef double f64x4 __attribute__((ext_vector_type(4)));

__device__ __forceinline__ float geluf(float x) {
  return 0.5f * x * (1.0f + erff(x * 0.70710678118654752440f));
}

// ---------------------------------------------------------------------------
// f64 MFMA GEMM (f32 in / f32 out), v_mfma_f64_16x16x4_f64 — LAYOUT-PROBED.
// 64x64 tile, BK=16, 4 waves, each wave a 32x32 quadrant (2x2 MFMA tiles).
// Before the K-loop, two probe MFMAs empirically determine the (lane,reg) ->
// (row,col) output mapping under OUR staging convention:
//   probe1 = mfma(A=staged m-values, B=1.0)  -> D slot value = 4*row
//   probe2 = mfma(A=1.0, B=staged n-values)  -> D slot value = 4*col
// (B=1.0 / A=1.0 from a uniform register is mapping-invariant.) The C-write
// scatters via the probed indices, so the kernel is correct for ANY
// factorized hardware fragment layout — this fixes r7's wrong-layout failure
// without knowing the right layout.
// CAUSAL: packed lower-triangular 1D grid. z-fusion as before.
// C[m][n] = (float)(alpha * sum_k A[m][k] * (BT ? B[n][k] : B[k][n]))
// ---------------------------------------------------------------------------
template<bool BT, bool CAUSAL>
__global__ void __launch_bounds__(256) gemm64p(
    const float* __restrict__ A, const float* __restrict__ Ba,
    const float* __restrict__ Bb, float* __restrict__ C,
    int N, int K, long sA, long sB, long sC, double alpha)
{
  int m0, n0;
  if (CAUSAL) {
    int l = blockIdx.x;
    int bi = (int)((sqrtf(8.0f * (float)l + 1.0f) - 1.0f) * 0.5f);
    while ((bi + 1) * (bi + 2) / 2 <= l) ++bi;
    while (bi * (bi + 1) / 2 > l) --bi;
    int bj = l - bi * (bi + 1) / 2;
    m0 = bi << 6; n0 = bj << 6;
  } else {
    m0 = blockIdx.y << 6; n0 = blockIdx.x << 6;
  }
  const int z = blockIdx.z;
  A += (size_t)z * sA;
  const float* B = (z ? Bb : Ba) + (size_t)z * sB;
  C += (size_t)z * sC;

  const int tid = threadIdx.x;
  const int w = tid >> 6, lane = tid & 63;
  const int kl = lane >> 4, lm = lane & 15;
  const int am0 = (w & 1) << 5;    // wave's row quadrant offset
  const int bn0 = (w >> 1) << 5;   // wave's col quadrant offset

  __shared__ double As[16][65];    // [k][m]
  __shared__ double Bs[16][65];    // [k][n]

  // ---------------- layout probe ----------------
  {
    int m = tid & 63, k4 = (tid >> 6) << 2;
#pragma unroll
    for (int q = 0; q < 4; ++q) {
      As[k4 + q][m] = (double)m;
      Bs[k4 + q][m] = (double)m;
    }
  }
  __syncthreads();
  int mr[4], nc[4];
  {
    double pa = As[kl][am0 + lm];
    double pb = Bs[kl][bn0 + lm];
    f64x4 d1 = {0.0, 0.0, 0.0, 0.0}, d2 = {0.0, 0.0, 0.0, 0.0};
    d1 = __builtin_amdgcn_mfma_f64_16x16x4f64(pa, 1.0, d1, 0, 0, 0);
    d2 = __builtin_amdgcn_mfma_f64_16x16x4f64(1.0, pb, d2, 0, 0, 0);
#pragma unroll
    for (int i = 0; i < 4; ++i) {
      mr[i] = ((int)d1[i]) >> 2;   // row coordinate in [0,64) incl. quadrant
      nc[i] = ((int)d2[i]) >> 2;   // col coordinate in [0,64) incl. quadrant
    }
  }
  __syncthreads();

  f64x4 c00 = {0.0, 0.0, 0.0, 0.0}, c01 = {0.0, 0.0, 0.0, 0.0};
  f64x4 c10 = {0.0, 0.0, 0.0, 0.0}, c11 = {0.0, 0.0, 0.0, 0.0};

  // staging ownership
  const int am = tid >> 2, akq = (tid & 3) << 2;   // A: row am, k akq..+3
  const int bk = tid >> 4, bn4 = (tid & 15) << 2;  // B !BT: k-row bk, cols bn4..+3
  const int tn = tid >> 2, tkq = (tid & 3) << 2;   // B  BT: n-row tn, k tkq..+3

  for (int k0 = 0; k0 < K; k0 += 16) {
    {
      float4 a = *(const float4*)(A + (size_t)(m0 + am) * K + k0 + akq);
      As[akq + 0][am] = (double)a.x; As[akq + 1][am] = (double)a.y;
      As[akq + 2][am] = (double)a.z; As[akq + 3][am] = (double)a.w;
    }
    if (!BT) {
      float4 b = *(const float4*)(B + (size_t)(k0 + bk) * N + n0 + bn4);
      Bs[bk][bn4 + 0] = (double)b.x; Bs[bk][bn4 + 1] = (double)b.y;
      Bs[bk][bn4 + 2] = (double)b.z; Bs[bk][bn4 + 3] = (double)b.w;
    } else {
      float4 b = *(const float4*)(B + (size_t)(n0 + tn) * K + k0 + tkq);
      Bs[tkq + 0][tn] = (double)b.x; Bs[tkq + 1][tn] = (double)b.y;
      Bs[tkq + 2][tn] = (double)b.z; Bs[tkq + 3][tn] = (double)b.w;
    }
    __syncthreads();
#pragma unroll
    for (int ks = 0; ks < 4; ++ks) {
      const int kr = (ks << 2) + kl;
      double a0 = As[kr][am0 + lm];
      double a1 = As[kr][am0 + 16 + lm];
      double b0 = Bs[kr][bn0 + lm];
      double b1 = Bs[kr][bn0 + 16 + lm];
      c00 = __builtin_amdgcn_mfma_f64_16x16x4f64(a0, b0, c00, 0, 0, 0);
      c01 = __builtin_amdgcn_mfma_f64_16x16x4f64(a0, b1, c01, 0, 0, 0);
      c10 = __builtin_amdgcn_mfma_f64_16x16x4f64(a1, b0, c10, 0, 0, 0);
      c11 = __builtin_amdgcn_mfma_f64_16x16x4f64(a1, b1, c11, 0, 0, 0);
    }
    __syncthreads();
  }

  // C-write via probed mapping (a1/b1 feed +16-shifted coordinates)
#pragma unroll
  for (int i = 0; i < 4; ++i) {
    const size_t r0 = (size_t)(m0 + mr[i]) * N;
    const size_t r1 = (size_t)(m0 + mr[i] + 16) * N;
    const int cA = n0 + nc[i], cB = cA + 16;
    C[r0 + cA] = (float)(c00[i] * alpha);
    C[r0 + cB] = (float)(c01[i] * alpha);
    C[r1 + cA] = (float)(c10[i] * alpha);
    C[r1 + cB] = (float)(c11[i] * alpha);
  }
}

// ---------------------------------------------------------------------------
// f32 GEMM, 64x128 tile, BK=16, 256 threads, 4x8 per thread (final V @ Wo).
// ---------------------------------------------------------------------------
__global__ void __launch_bounds__(256) gemm128b(const float* __restrict__ A,
                                                const float* __restrict__ B,
                                                float* __restrict__ C,
                                                int M, int N, int K, float alpha)
{
  const int m0 = blockIdx.y << 6, n0 = blockIdx.x << 7;
  const int tid = threadIdx.x;
  const int tx = tid & 15, ty = tid >> 4;

  __shared__ float As[16][68];
  __shared__ float Bs[16][132];

  float acc[4][8];
#pragma unroll
  for (int i = 0; i < 4; ++i)
#pragma unroll
    for (int j = 0; j < 8; ++j) acc[i][j] = 0.f;

  for (int k0 = 0; k0 < K; k0 += 16) {
    {
      int m = tid >> 2, kq = (tid & 3) << 2;
      float4 a = *(const float4*)(A + (size_t)(m0 + m) * K + k0 + kq);
      As[kq + 0][m] = a.x; As[kq + 1][m] = a.y; As[kq + 2][m] = a.z; As[kq + 3][m] = a.w;
    }
#pragma unroll
    for (int rep = 0; rep < 2; ++rep) {
      int q = tid + (rep << 8);
      int kk = q >> 5, n4 = q & 31;
      *(float4*)&Bs[kk][n4 << 2] =
          *(const float4*)(B + (size_t)(k0 + kk) * N + n0 + (n4 << 2));
    }
    __syncthreads();
#pragma unroll
    for (int kk = 0; kk < 16; ++kk) {
      float4 a = *(const float4*)&As[kk][ty << 2];
      float4 b0 = *(const float4*)&Bs[kk][tx << 3];
      float4 b1 = *(const float4*)&Bs[kk][(tx << 3) + 4];
      float av[4] = {a.x, a.y, a.z, a.w};
      float bv[8] = {b0.x, b0.y, b0.z, b0.w, b1.x, b1.y, b1.z, b1.w};
#pragma unroll
      for (int i = 0; i < 4; ++i)
#pragma unroll
        for (int j = 0; j < 8; ++j)
          acc[i][j] = fmaf(av[i], bv[j], acc[i][j]);
    }
    __syncthreads();
  }
#pragma unroll
  for (int i = 0; i < 4; ++i) {
    size_t coff = (size_t)(m0 + (ty << 2) + i) * N + n0 + (tx << 3);
    float4 o0 = make_float4(acc[i][0] * alpha, acc[i][1] * alpha, acc[i][2] * alpha, acc[i][3] * alpha);
    float4 o1 = make_float4(acc[i][4] * alpha, acc[i][5] * alpha, acc[i][6] * alpha, acc[i][7] * alpha);
    *(float4*)(C + coff) = o0;
    *(float4*)(C + coff + 4) = o1;
  }
}

// ---------------------------------------------------------------------------
// Trig table: EXACT reference f32 bits (corr-rounded pow, f32 angle multiply,
// corr-rounded f32 cos/sin via f64 sincos of the f32 argument).
// ---------------------------------------------------------------------------
__global__ void __launch_bounds__(256) trig_table_kernel(float2* __restrict__ tab)
{
  const int t = blockIdx.x;
  for (int j = threadIdx.x; j < 512; j += 256) {
    double e = (double)j * (1.0 / 512.0);
    float pf = (float)pow(10000.0, e);
    float invf = 1.0f / pf;
    float angf = (float)t * invf;
    double s64, c64;
    sincos((double)angf, &s64, &c64);
    tab[(size_t)t * 512 + j] = make_float2((float)c64, (float)s64);
  }
}

// ---------------------------------------------------------------------------
// RoPE in place + row L2 norms, reading the trig table. f32 rotation with
// no-contract ops. DO NOT change — selection-critical.
// ---------------------------------------------------------------------------
__global__ void __launch_bounds__(256) rope_norm_kernel(float* __restrict__ bI,
                                                        float* __restrict__ bP,
                                                        const float2* __restrict__ tab,
                                                        float* __restrict__ nI,
                                                        float* __restrict__ nP)
{
  const int row = blockIdx.x;
  const int t = row & (T_LEN - 1);
  const int tid = threadIdx.x;
  __shared__ double redI[4], redP[4];
  double ssI = 0.0, ssP = 0.0;
  const size_t off = (size_t)row * D_DIM;
  for (int j = tid; j < 512; j += 256) {
    float2 cs = tab[(size_t)t * 512 + j];
    float c = cs.x, s = cs.y;

    float a1 = bI[off + j], a2 = bI[off + 512 + j];
    float o1 = __fsub_rn(__fmul_rn(a1, c), __fmul_rn(a2, s));
    float o2 = __fadd_rn(__fmul_rn(a1, s), __fmul_rn(a2, c));
    bI[off + j] = o1; bI[off + 512 + j] = o2;
    ssI += (double)o1 * o1 + (double)o2 * o2;

    float p1 = bP[off + j], p2 = bP[off + 512 + j];
    float q1 = __fsub_rn(__fmul_rn(p1, c), __fmul_rn(p2, s));
    float q2 = __fadd_rn(__fmul_rn(p1, s), __fmul_rn(p2, c));
    bP[off + j] = q1; bP[off + 512 + j] = q2;
    ssP += (double)q1 * q1 + (double)q2 * q2;
  }
#pragma unroll
  for (int o = 32; o >= 1; o >>= 1) { ssI += __shfl_xor(ssI, o); ssP += __shfl_xor(ssP, o); }
  if ((tid & 63) == 0) { redI[tid >> 6] = ssI; redP[tid >> 6] = ssP; }
  __syncthreads();
  if (tid == 0) {
    nI[row] = fmaxf((float)sqrt(redI[0] + redI[1] + redI[2] + redI[3]), 1e-12f);
    nP[row] = fmaxf((float)sqrt(redP[0] + redP[1] + redP[2] + redP[3]), 1e-12f);
  }
}

// ---------------------------------------------------------------------------
// palette (D x 256) -> palT (256 x D)
// ---------------------------------------------------------------------------
__global__ void transpose_pal(const float* __restrict__ pal, float* __restrict__ palT)
{
  int c = blockIdx.x;
  int d = blockIdx.y * 256 + threadIdx.x;
  palT[(size_t)c * D_DIM + d] = pal[(size_t)d * 256 + c];
}

// ---------------------------------------------------------------------------
// Top-15 per causal row. One wave per row. Descending; ties -> lower index.
// ---------------------------------------------------------------------------
__global__ void __launch_bounds__(256) topk_kernel(const float* __restrict__ S,
                                                   int* __restrict__ idx, int b)
{
  const int wave = threadIdx.x >> 6, lane = threadIdx.x & 63;
  const int t = blockIdx.x * 4 + wave;
  const float* rowp = S + (size_t)t * T_LEN;
  float v[32];
#pragma unroll
  for (int i = 0; i < 32; ++i) {
    int s = lane + (i << 6);
    v[i] = (s <= t) ? rowp[s] : -INFINITY;
  }
  float pv = INFINITY; int pidx = -1;
  int* outp = idx + ((size_t)b * T_LEN + t) * 16;
  for (int k = 0; k < KSEL; ++k) {
    float bv = -INFINITY; int bi = 0x7fffffff;
#pragma unroll
    for (int i = 0; i < 32; ++i) {
      int s = lane + (i << 6);
      float vv = v[i];
      bool elig = (vv < pv) || (vv == pv && s > pidx);
      if (elig && vv > bv) { bv = vv; bi = s; }
    }
#pragma unroll
    for (int o = 32; o >= 1; o >>= 1) {
      float ov = __shfl_xor(bv, o);
      int oi = __shfl_xor(bi, o);
      if (ov > bv || (ov == bv && oi < bi)) { bv = ov; bi = oi; }
    }
    pv = bv; pidx = bi;
    if (lane == 0) outp[k] = (bi == 0x7fffffff || bv == -INFINITY) ? 0 : bi;
  }
}

// ---------------------------------------------------------------------------
// Per-(b,t): gather + normalized gram + rel features + MLP + heads + softmax
// + bilinear palette blend -> V[b,t,:].
// ---------------------------------------------------------------------------
__global__ void __launch_bounds__(256) relmlp_kernel(
    const float* __restrict__ I, const float* __restrict__ P,
    const float* __restrict__ nI, const float* __restrict__ nP,
    const int* __restrict__ topk,
    const float* __restrict__ W1, const float* __restrict__ b1,
    const float* __restrict__ W2, const float* __restrict__ b2,
    const float* __restrict__ Wc, const float* __restrict__ bc,
    const float* __restrict__ Wm, const float* __restrict__ bm,
    const float* __restrict__ palT, float* __restrict__ V)
{
  const int row = blockIdx.x;
  const int t = row & (T_LEN - 1);
  const int base = row & ~(T_LEN - 1);
  const int nk = (t + 1 < KSEL) ? (t + 1) : KSEL;
  const int tid = threadIdx.x;

  __shared__ float vecS[16][516];
  __shared__ float gS[16][16];
  __shared__ float relS[KSEL][17];
  __shared__ float h1S[KSEL][HIDN];
  __shared__ float h2S[KSEL][HIDN];
  __shared__ float nrmS[16];
  __shared__ int   sidxS[16];
  __shared__ float mixS[KSEL], wS[KSEL], zxS[KSEL], zyS[KSEL];
  __shared__ float coefS[4 * KSEL];
  __shared__ int   cellS[4 * KSEL];

  if (tid < 16) {
    int s = t;
    if (tid >= 1) s = (tid <= nk) ? topk[(size_t)row * 16 + (tid - 1)] : 0;
    sidxS[tid] = s;
    nrmS[tid] = (tid == 0) ? nI[row] : nP[base + s];
  }
  __syncthreads();

  const int r = tid >> 4, c0 = tid & 15;
  const float* srcrow = (r == 0) ? (I + (size_t)row * D_DIM)
                                 : (P + ((size_t)base + sidxS[r]) * D_DIM);

  int pi = 0, pj = 0;
  {
    int p = tid;
    if (p < 136) {
      int i = 0;
      while (p >= 16 - i) { p -= 16 - i; ++i; }
      pi = i; pj = i + p;
    }
  }
  const bool pairOn = (tid < 136) && (pi <= nk) && (pj <= nk);
  float4 acc4 = make_float4(0.f, 0.f, 0.f, 0.f);

  for (int half = 0; half < 2; ++half) {
    if (half) __syncthreads();
    if (r <= nk) {
#pragma unroll
      for (int rep = 0; rep < 8; ++rep) {
        int q = c0 + 16 * rep;
        float4 v4 = *(const float4*)(srcrow + half * 512 + (q << 2));
        *(float4*)&vecS[r][q << 2] = v4;
      }
    }
    __syncthreads();
    if (pairOn) {
      const float4* va = (const float4*)&vecS[pi][0];
      const float4* vb = (const float4*)&vecS[pj][0];
#pragma unroll 4
      for (int q = 0; q < 128; ++q) {
        float4 a4 = va[q], b4 = vb[q];
        acc4.x = fmaf(a4.x, b4.x, acc4.x);
        acc4.y = fmaf(a4.y, b4.y, acc4.y);
        acc4.z = fmaf(a4.z, b4.z, acc4.z);
        acc4.w = fmaf(a4.w, b4.w, acc4.w);
      }
    }
  }
  if (tid < 136) {
    float g = 0.f;
    if (pairOn) {
      float acc = (acc4.x + acc4.y) + (acc4.z + acc4.w);
      g = acc / (nrmS[pi] * nrmS[pj]);
      g = fminf(fmaxf(g, -1.f), 1.f);
    }
    gS[pi][pj] = g;
    gS[pj][pi] = g;
  }
  __syncthreads();

  if (tid < KSEL * 17) {
    int k = tid / 17, f = tid % 17;
    float v = 0.f;
    if (k < nk) {
      if (f < KSEL)        v = (f < nk) ? gS[k + 1][f + 1] : 0.f;
      else if (f == KSEL)  v = gS[0][k + 1];
      else                 v = (float)(t - sidxS[k + 1]) * (1.0f / (float)T_LEN);
    }
    relS[k][f] = v;
  }
  __syncthreads();

  for (int o = tid; o < KSEL * HIDN; o += 256) {
    int k = o >> 6, m = o & 63;
    float a = b1[m];
#pragma unroll
    for (int f = 0; f < 17; ++f) a = fmaf(relS[k][f], W1[f * HIDN + m], a);
    h1S[k][m] = geluf(a);
  }
  __syncthreads();
  for (int o = tid; o < KSEL * HIDN; o += 256) {
    int k = o >> 6, m = o & 63;
    float a = b2[m];
#pragma unroll 8
    for (int n = 0; n < HIDN; ++n) a = fmaf(h1S[k][n], W2[n * HIDN + m], a);
    h2S[k][m] = geluf(a);
  }
  __syncthreads();
  if (tid < KSEL) {
    float a0 = 0.f, a1 = 0.f, am = 0.f;
#pragma unroll 8
    for (int n = 0; n < HIDN; ++n) {
      float h = h2S[tid][n];
      a0 = fmaf(h, Wc[n * 2 + 0], a0);
      a1 = fmaf(h, Wc[n * 2 + 1], a1);
      am = fmaf(h, Wm[n], am);
    }
    zxS[tid] = tanhf(a0 + bc[0]);
    zyS[tid] = tanhf(a1 + bc[1]);
    mixS[tid] = am + bm[0];
  }
  __syncthreads();
  if (tid == 0) {
    float mx = -INFINITY;
    for (int k = 0; k < nk; ++k) mx = fmaxf(mx, mixS[k]);
    float ssum = 0.f;
    for (int k = 0; k < nk; ++k) { float e = expf(mixS[k] - mx); wS[k] = e; ssum += e; }
    float inv = 1.f / ssum;
    for (int k = 0; k < nk; ++k) wS[k] *= inv;
  }
  __syncthreads();
  if (tid < KSEL) {
    int k = tid;
    if (k < nk) {
      float w = wS[k];
      float fx = fminf(fmaxf((zxS[k] + 1.f) * 0.5f * 15.f, 0.f), 15.f);
      float fy = fminf(fmaxf((zyS[k] + 1.f) * 0.5f * 15.f, 0.f), 15.f);
      int x0 = (int)floorf(fx); int x1i = (x0 + 1 < 15) ? x0 + 1 : 15;
      int y0 = (int)floorf(fy); int y1i = (y0 + 1 < 15) ? y0 + 1 : 15;
      float wx = fx - (float)x0, wy = fy - (float)y0;
      cellS[k * 4 + 0] = y0 * 16 + x0;   coefS[k * 4 + 0] = w * (1.f - wy) * (1.f - wx);
      cellS[k * 4 + 1] = y0 * 16 + x1i;  coefS[k * 4 + 1] = w * (1.f - wy) * wx;
      cellS[k * 4 + 2] = y1i * 16 + x0;  coefS[k * 4 + 2] = w * wy * (1.f - wx);
      cellS[k * 4 + 3] = y1i * 16 + x1i; coefS[k * 4 + 3] = w * wy * wx;
    } else {
      cellS[k * 4 + 0] = cellS[k * 4 + 1] = cellS[k * 4 + 2] = cellS[k * 4 + 3] = 0;
      coefS[k * 4 + 0] = coefS[k * 4 + 1] = coefS[k * 4 + 2] = coefS[k * 4 + 3] = 0.f;
    }
  }
  __syncthreads();
  const int nj = 4 * nk;
  for (int d = tid; d < D_DIM; d += 256) {
    float a = 0.f;
    for (int j = 0; j < nj; ++j)
      a = fmaf(coefS[j], palT[(size_t)cellS[j] * D_DIM + d], a);
    V[(size_t)row * D_DIM + d] = a;
  }
}

// ---------------------------------------------------------------------------
// Host launcher. Workspace (floats, ~65.3 MiB):
//   palT | I | P | S(32MB; trig table + V alias into it, all sequential) | norms | idx
// ---------------------------------------------------------------------------
extern "C" void kernel_launch(void* const* d_in, const int* in_sizes, int n_in,
                              void* d_out, int out_size, void* d_ws, size_t ws_size,
                              hipStream_t stream)
{
  (void)in_sizes; (void)n_in; (void)out_size; (void)ws_size;
  const float* x   = (const float*)d_in[0];
  const float* Wi  = (const float*)d_in[1];
  const float* Wp  = (const float*)d_in[2];
  const float* pal = (const float*)d_in[3];
  const float* W1  = (const float*)d_in[4];
  const float* b1  = (const float*)d_in[5];
  const float* W2  = (const float*)d_in[6];
  const float* b2  = (const float*)d_in[7];
  const float* Wc  = (const float*)d_in[8];
  const float* bc  = (const float*)d_in[9];
  const float* Wm  = (const float*)d_in[10];
  const float* bm  = (const float*)d_in[11];
  const float* Wo  = (const float*)d_in[12];
  float* out = (float*)d_out;

  float* w = (float*)d_ws;
  float* palT = w;  w += (size_t)256 * D_DIM;
  float* I    = w;  w += (size_t)BATCH * T_LEN * D_DIM;
  float* P    = w;  w += (size_t)BATCH * T_LEN * D_DIM;
  float* Sb   = w;  w += (size_t)BATCH * T_LEN * T_LEN;   // hosts tab & V sequentially
  float* nIb  = w;  w += (size_t)BATCH * T_LEN;
  float* nPb  = w;  w += (size_t)BATCH * T_LEN;
  int*   idx  = (int*)w;

  float2* tab = (float2*)Sb;   // consumed by rope BEFORE S is written
  float*  Vb  = Sb;            // V written AFTER topk consumed S

  const int MROWS = BATCH * T_LEN;  // 4096

  trig_table_kernel<<<T_LEN, 256, 0, stream>>>(tab);
  transpose_pal<<<dim3(256, 4), 256, 0, stream>>>(pal, palT);

  // I = x@Wi (z=0), P = x@Wp (z=1): one fused MFMA launch, 2048 blocks.
  gemm64p<false, false><<<dim3(D_DIM / 64, MROWS / 64, 2), 256, 0, stream>>>(
      x, Wi, Wp, I, D_DIM, D_DIM,
      0L, 0L, (long)MROWS * D_DIM, 1.0);

  rope_norm_kernel<<<MROWS, 256, 0, stream>>>(I, P, tab, nIb, nPb);

  // S[b] = (I_b @ P_b^T) * D^-0.5, packed lower-triangular grid, both batches.
  const int NT = T_LEN / 64;                 // 32
  const int NTRI = NT * (NT + 1) / 2;        // 528
  gemm64p<true, true><<<dim3(NTRI, 1, 2), 256, 0, stream>>>(
      I, P, P, Sb, T_LEN, D_DIM,
      (long)T_LEN * D_DIM, (long)T_LEN * D_DIM, (long)T_LEN * T_LEN, 0.03125);

  for (int b = 0; b < BATCH; ++b)
    topk_kernel<<<T_LEN / 4, 256, 0, stream>>>(Sb + (size_t)b * T_LEN * T_LEN, idx, b);

  relmlp_kernel<<<MROWS, 256, 0, stream>>>(I, P, nIb, nPb, idx,
                                           W1, b1, W2, b2, Wc, bc, Wm, bm,
                                           palT, Vb);

  gemm128b<<<dim3(D_DIM / 128, MROWS / 64), 256, 0, stream>>>(
      Vb, Wo, out, MROWS, D_DIM, D_DIM, 1.0f);
}

// Round 9
// 884.222 us; speedup vs baseline: 2.3201x; 1.0568x over previous
//
#include <hip/hip_runtime.h>
#include <math.h>

// Problem constants (fixed by the reference)
#define BATCH 2
#define T_LEN 2048
#define D_DIM 1024
#define KSEL  15
#define HIDN  64

typedef double f64x4 __attribute__((ext_vector_type(4)));

__device__ __forceinline__ float geluf(float x) {
  return 0.5f * x * (1.0f + erff(x * 0.70710678118654752440f));
}

// ---------------------------------------------------------------------------
// f64 MFMA GEMM v2 (f32 in / f32 out), v_mfma_f64_16x16x4_f64, LAYOUT-PROBED
// (r8's working probe), now 64x128 tile + LDS DOUBLE-BUFFER + reg prefetch.
// 4 waves; wave w owns a 32x64 quadrant: 2 row-tiles x 4 col-tiles of 16x16
// (8 MFMA per 6 LDS reads, vs r8's 4:4). acc = 8 x f64x4 = 64 VGPR, so the
// dbuf prefetch fits without the r6 VGPR blowup. One barrier per K-step;
// global loads for step k+1 issue before compute of step k -> L3/HBM latency
// hides under ~2k cycles of MFMA.
// CAUSAL: packed grid, count(bi) = (bi>>1)+1 tiles (BN=128 vs BM=64);
// in-tile upper-triangle cells are computed but never read (topk masks s<=t).
// z-fusion as before.
// C[m][n] = (float)(alpha * sum_k A[m][k] * (BT ? B[n][k] : B[k][n]))
// ---------------------------------------------------------------------------
template<bool BT, bool CAUSAL>
__global__ void __launch_bounds__(256, 3) gemm64q(
    const float* __restrict__ A, const float* __restrict__ Ba,
    const float* __restrict__ Bb, float* __restrict__ C,
    int N, int K, long sA, long sB, long sC, double alpha)
{
  int m0, n0;
  if (CAUSAL) {
    int rem = blockIdx.x, bi = 0;
    while (rem >= (bi >> 1) + 1) { rem -= (bi >> 1) + 1; ++bi; }
    m0 = bi << 6; n0 = rem << 7;
  } else {
    m0 = blockIdx.y << 6; n0 = blockIdx.x << 7;
  }
  const int z = blockIdx.z;
  A += (size_t)z * sA;
  const float* B = (z ? Bb : Ba) + (size_t)z * sB;
  C += (size_t)z * sC;

  const int tid = threadIdx.x;
  const int w = tid >> 6, lane = tid & 63;
  const int kl = lane >> 4, lm = lane & 15;
  const int am0 = (w & 1) << 5;    // wave's 32-row quadrant
  const int bn0 = (w >> 1) << 6;   // wave's 64-col half

  __shared__ double As[2][16][66];    // [buf][k][m]
  __shared__ double Bs[2][16][130];   // [buf][k][n]

  // ---------------- layout probe (buf 0) ----------------
  {
    int m = tid & 63, k4 = (tid >> 6) << 2;
#pragma unroll
    for (int q = 0; q < 4; ++q) As[0][k4 + q][m] = (double)m;
    int n = tid & 127, k8 = (tid >> 7) << 3;
#pragma unroll
    for (int q = 0; q < 8; ++q) Bs[0][k8 + q][n] = (double)n;
  }
  __syncthreads();
  int mr[4], nc[4];
  {
    double pa = As[0][kl][am0 + lm];
    double pb = Bs[0][kl][bn0 + lm];
    f64x4 d1 = {0.0, 0.0, 0.0, 0.0}, d2 = {0.0, 0.0, 0.0, 0.0};
    d1 = __builtin_amdgcn_mfma_f64_16x16x4f64(pa, 1.0, d1, 0, 0, 0);
    d2 = __builtin_amdgcn_mfma_f64_16x16x4f64(1.0, pb, d2, 0, 0, 0);
#pragma unroll
    for (int i = 0; i < 4; ++i) {
      mr[i] = ((int)d1[i]) >> 2;   // row in [0,64) incl. quadrant offset
      nc[i] = ((int)d2[i]) >> 2;   // col in [0,128) incl. half offset (tile j=0)
    }
  }
  __syncthreads();

  f64x4 c00 = {0,0,0,0}, c01 = {0,0,0,0}, c02 = {0,0,0,0}, c03 = {0,0,0,0};
  f64x4 c10 = {0,0,0,0}, c11 = {0,0,0,0}, c12 = {0,0,0,0}, c13 = {0,0,0,0};

  // staging ownership
  const int am = tid >> 2, akq = (tid & 3) << 2;   // A: row am, k akq..+3
  const int bk = tid >> 4, bn8 = (tid & 15) << 3;  // B !BT: k-row bk, cols bn8..+7
  const int tn = tid >> 1, tkq = (tid & 1) << 3;   // B  BT: n-row tn, k tkq..+7

  float4 ra, rb0, rb1;

  // prologue: load k0=0 into regs, stage to buf 0
  ra = *(const float4*)(A + (size_t)(m0 + am) * K + akq);
  if (!BT) {
    const float* bp = B + (size_t)bk * N + n0 + bn8;
    rb0 = *(const float4*)(bp); rb1 = *(const float4*)(bp + 4);
  } else {
    const float* bp = B + (size_t)(n0 + tn) * K + tkq;
    rb0 = *(const float4*)(bp); rb1 = *(const float4*)(bp + 4);
  }
  {
    As[0][akq + 0][am] = (double)ra.x; As[0][akq + 1][am] = (double)ra.y;
    As[0][akq + 2][am] = (double)ra.z; As[0][akq + 3][am] = (double)ra.w;
    if (!BT) {
      Bs[0][bk][bn8 + 0] = (double)rb0.x; Bs[0][bk][bn8 + 1] = (double)rb0.y;
      Bs[0][bk][bn8 + 2] = (double)rb0.z; Bs[0][bk][bn8 + 3] = (double)rb0.w;
      Bs[0][bk][bn8 + 4] = (double)rb1.x; Bs[0][bk][bn8 + 5] = (double)rb1.y;
      Bs[0][bk][bn8 + 6] = (double)rb1.z; Bs[0][bk][bn8 + 7] = (double)rb1.w;
    } else {
      Bs[0][tkq + 0][tn] = (double)rb0.x; Bs[0][tkq + 1][tn] = (double)rb0.y;
      Bs[0][tkq + 2][tn] = (double)rb0.z; Bs[0][tkq + 3][tn] = (double)rb0.w;
      Bs[0][tkq + 4][tn] = (double)rb1.x; Bs[0][tkq + 5][tn] = (double)rb1.y;
      Bs[0][tkq + 6][tn] = (double)rb1.z; Bs[0][tkq + 7][tn] = (double)rb1.w;
    }
  }
  __syncthreads();

  int buf = 0;
  for (int k0 = 0; k0 < K; k0 += 16) {
    const bool more = (k0 + 16) < K;
    if (more) {
      const int kn = k0 + 16;
      ra = *(const float4*)(A + (size_t)(m0 + am) * K + kn + akq);
      if (!BT) {
        const float* bp = B + (size_t)(kn + bk) * N + n0 + bn8;
        rb0 = *(const float4*)(bp); rb1 = *(const float4*)(bp + 4);
      } else {
        const float* bp = B + (size_t)(n0 + tn) * K + kn + tkq;
        rb0 = *(const float4*)(bp); rb1 = *(const float4*)(bp + 4);
      }
    }
#pragma unroll
    for (int ks = 0; ks < 4; ++ks) {
      const int kr = (ks << 2) + kl;
      double a0 = As[buf][kr][am0 + lm];
      double a1 = As[buf][kr][am0 + 16 + lm];
      double b0 = Bs[buf][kr][bn0 + lm];
      double b1 = Bs[buf][kr][bn0 + 16 + lm];
      double b2 = Bs[buf][kr][bn0 + 32 + lm];
      double b3 = Bs[buf][kr][bn0 + 48 + lm];
      c00 = __builtin_amdgcn_mfma_f64_16x16x4f64(a0, b0, c00, 0, 0, 0);
      c01 = __builtin_amdgcn_mfma_f64_16x16x4f64(a0, b1, c01, 0, 0, 0);
      c02 = __builtin_amdgcn_mfma_f64_16x16x4f64(a0, b2, c02, 0, 0, 0);
      c03 = __builtin_amdgcn_mfma_f64_16x16x4f64(a0, b3, c03, 0, 0, 0);
      c10 = __builtin_amdgcn_mfma_f64_16x16x4f64(a1, b0, c10, 0, 0, 0);
      c11 = __builtin_amdgcn_mfma_f64_16x16x4f64(a1, b1, c11, 0, 0, 0);
      c12 = __builtin_amdgcn_mfma_f64_16x16x4f64(a1, b2, c12, 0, 0, 0);
      c13 = __builtin_amdgcn_mfma_f64_16x16x4f64(a1, b3, c13, 0, 0, 0);
    }
    if (more) {
      const int nb = buf ^ 1;
      As[nb][akq + 0][am] = (double)ra.x; As[nb][akq + 1][am] = (double)ra.y;
      As[nb][akq + 2][am] = (double)ra.z; As[nb][akq + 3][am] = (double)ra.w;
      if (!BT) {
        Bs[nb][bk][bn8 + 0] = (double)rb0.x; Bs[nb][bk][bn8 + 1] = (double)rb0.y;
        Bs[nb][bk][bn8 + 2] = (double)rb0.z; Bs[nb][bk][bn8 + 3] = (double)rb0.w;
        Bs[nb][bk][bn8 + 4] = (double)rb1.x; Bs[nb][bk][bn8 + 5] = (double)rb1.y;
        Bs[nb][bk][bn8 + 6] = (double)rb1.z; Bs[nb][bk][bn8 + 7] = (double)rb1.w;
      } else {
        Bs[nb][tkq + 0][tn] = (double)rb0.x; Bs[nb][tkq + 1][tn] = (double)rb0.y;
        Bs[nb][tkq + 2][tn] = (double)rb0.z; Bs[nb][tkq + 3][tn] = (double)rb0.w;
        Bs[nb][tkq + 4][tn] = (double)rb1.x; Bs[nb][tkq + 5][tn] = (double)rb1.y;
        Bs[nb][tkq + 6][tn] = (double)rb1.z; Bs[nb][tkq + 7][tn] = (double)rb1.w;
      }
    }
    __syncthreads();
    buf ^= 1;
  }

  // C-write via probed mapping (row-tile +16, col-tiles +16j by linearity)
#pragma unroll
  for (int i = 0; i < 4; ++i) {
    const size_t r0 = (size_t)(m0 + mr[i]) * N;
    const size_t r1 = r0 + (size_t)16 * N;
    const int c = n0 + nc[i];
    C[r0 + c +  0] = (float)(c00[i] * alpha);
    C[r0 + c + 16] = (float)(c01[i] * alpha);
    C[r0 + c + 32] = (float)(c02[i] * alpha);
    C[r0 + c + 48] = (float)(c03[i] * alpha);
    C[r1 + c +  0] = (float)(c10[i] * alpha);
    C[r1 + c + 16] = (float)(c11[i] * alpha);
    C[r1 + c + 32] = (float)(c12[i] * alpha);
    C[r1 + c + 48] = (float)(c13[i] * alpha);
  }
}

// ---------------------------------------------------------------------------
// f32 GEMM, 64x128 tile, BK=16, 256 threads, 4x8 per thread (final V @ Wo).
// ---------------------------------------------------------------------------
__global__ void __launch_bounds__(256) gemm128b(const float* __restrict__ A,
                                                const float* __restrict__ B,
                                                float* __restrict__ C,
                                                int M, int N, int K, float alpha)
{
  const int m0 = blockIdx.y << 6, n0 = blockIdx.x << 7;
  const int tid = threadIdx.x;
  const int tx = tid & 15, ty = tid >> 4;

  __shared__ float As[16][68];
  __shared__ float Bs[16][132];

  float acc[4][8];
#pragma unroll
  for (int i = 0; i < 4; ++i)
#pragma unroll
    for (int j = 0; j < 8; ++j) acc[i][j] = 0.f;

  for (int k0 = 0; k0 < K; k0 += 16) {
    {
      int m = tid >> 2, kq = (tid & 3) << 2;
      float4 a = *(const float4*)(A + (size_t)(m0 + m) * K + k0 + kq);
      As[kq + 0][m] = a.x; As[kq + 1][m] = a.y; As[kq + 2][m] = a.z; As[kq + 3][m] = a.w;
    }
#pragma unroll
    for (int rep = 0; rep < 2; ++rep) {
      int q = tid + (rep << 8);
      int kk = q >> 5, n4 = q & 31;
      *(float4*)&Bs[kk][n4 << 2] =
          *(const float4*)(B + (size_t)(k0 + kk) * N + n0 + (n4 << 2));
    }
    __syncthreads();
#pragma unroll
    for (int kk = 0; kk < 16; ++kk) {
      float4 a = *(const float4*)&As[kk][ty << 2];
      float4 b0 = *(const float4*)&Bs[kk][tx << 3];
      float4 b1 = *(const float4*)&Bs[kk][(tx << 3) + 4];
      float av[4] = {a.x, a.y, a.z, a.w};
      float bv[8] = {b0.x, b0.y, b0.z, b0.w, b1.x, b1.y, b1.z, b1.w};
#pragma unroll
      for (int i = 0; i < 4; ++i)
#pragma unroll
        for (int j = 0; j < 8; ++j)
          acc[i][j] = fmaf(av[i], bv[j], acc[i][j]);
    }
    __syncthreads();
  }
#pragma unroll
  for (int i = 0; i < 4; ++i) {
    size_t coff = (size_t)(m0 + (ty << 2) + i) * N + n0 + (tx << 3);
    float4 o0 = make_float4(acc[i][0] * alpha, acc[i][1] * alpha, acc[i][2] * alpha, acc[i][3] * alpha);
    float4 o1 = make_float4(acc[i][4] * alpha, acc[i][5] * alpha, acc[i][6] * alpha, acc[i][7] * alpha);
    *(float4*)(C + coff) = o0;
    *(float4*)(C + coff + 4) = o1;
  }
}

// ---------------------------------------------------------------------------
// Trig table: EXACT reference f32 bits (corr-rounded pow, f32 angle multiply,
// corr-rounded f32 cos/sin via f64 sincos of the f32 argument).
// ---------------------------------------------------------------------------
__global__ void __launch_bounds__(256) trig_table_kernel(float2* __restrict__ tab)
{
  const int t = blockIdx.x;
  for (int j = threadIdx.x; j < 512; j += 256) {
    double e = (double)j * (1.0 / 512.0);
    float pf = (float)pow(10000.0, e);
    float invf = 1.0f / pf;
    float angf = (float)t * invf;
    double s64, c64;
    sincos((double)angf, &s64, &c64);
    tab[(size_t)t * 512 + j] = make_float2((float)c64, (float)s64);
  }
}

// ---------------------------------------------------------------------------
// RoPE in place + row L2 norms, reading the trig table. f32 rotation with
// no-contract ops. DO NOT change — selection-critical.
// ---------------------------------------------------------------------------
__global__ void __launch_bounds__(256) rope_norm_kernel(float* __restrict__ bI,
                                                        float* __restrict__ bP,
                                                        const float2* __restrict__ tab,
                                                        float* __restrict__ nI,
                                                        float* __restrict__ nP)
{
  const int row = blockIdx.x;
  const int t = row & (T_LEN - 1);
  const int tid = threadIdx.x;
  __shared__ double redI[4], redP[4];
  double ssI = 0.0, ssP = 0.0;
  const size_t off = (size_t)row * D_DIM;
  for (int j = tid; j < 512; j += 256) {
    float2 cs = tab[(size_t)t * 512 + j];
    float c = cs.x, s = cs.y;

    float a1 = bI[off + j], a2 = bI[off + 512 + j];
    float o1 = __fsub_rn(__fmul_rn(a1, c), __fmul_rn(a2, s));
    float o2 = __fadd_rn(__fmul_rn(a1, s), __fmul_rn(a2, c));
    bI[off + j] = o1; bI[off + 512 + j] = o2;
    ssI += (double)o1 * o1 + (double)o2 * o2;

    float p1 = bP[off + j], p2 = bP[off + 512 + j];
    float q1 = __fsub_rn(__fmul_rn(p1, c), __fmul_rn(p2, s));
    float q2 = __fadd_rn(__fmul_rn(p1, s), __fmul_rn(p2, c));
    bP[off + j] = q1; bP[off + 512 + j] = q2;
    ssP += (double)q1 * q1 + (double)q2 * q2;
  }
#pragma unroll
  for (int o = 32; o >= 1; o >>= 1) { ssI += __shfl_xor(ssI, o); ssP += __shfl_xor(ssP, o); }
  if ((tid & 63) == 0) { redI[tid >> 6] = ssI; redP[tid >> 6] = ssP; }
  __syncthreads();
  if (tid == 0) {
    nI[row] = fmaxf((float)sqrt(redI[0] + redI[1] + redI[2] + redI[3]), 1e-12f);
    nP[row] = fmaxf((float)sqrt(redP[0] + redP[1] + redP[2] + redP[3]), 1e-12f);
  }
}

// ---------------------------------------------------------------------------
// palette (D x 256) -> palT (256 x D)
// ---------------------------------------------------------------------------
__global__ void transpose_pal(const float* __restrict__ pal, float* __restrict__ palT)
{
  int c = blockIdx.x;
  int d = blockIdx.y * 256 + threadIdx.x;
  palT[(size_t)c * D_DIM + d] = pal[(size_t)d * 256 + c];
}

// ---------------------------------------------------------------------------
// Top-15 per causal row, both batches (blockIdx.y = b). One wave per row.
// Descending; ties -> lower index.
// ---------------------------------------------------------------------------
__global__ void __launch_bounds__(256) topk_kernel(const float* __restrict__ Sb,
                                                   int* __restrict__ idx)
{
  const int b = blockIdx.y;
  const float* S = Sb + (size_t)b * T_LEN * T_LEN;
  const int wave = threadIdx.x >> 6, lane = threadIdx.x & 63;
  const int t = blockIdx.x * 4 + wave;
  const float* rowp = S + (size_t)t * T_LEN;
  float v[32];
#pragma unroll
  for (int i = 0; i < 32; ++i) {
    int s = lane + (i << 6);
    v[i] = (s <= t) ? rowp[s] : -INFINITY;
  }
  float pv = INFINITY; int pidx = -1;
  int* outp = idx + ((size_t)b * T_LEN + t) * 16;
  for (int k = 0; k < KSEL; ++k) {
    float bv = -INFINITY; int bi = 0x7fffffff;
#pragma unroll
    for (int i = 0; i < 32; ++i) {
      int s = lane + (i << 6);
      float vv = v[i];
      bool elig = (vv < pv) || (vv == pv && s > pidx);
      if (elig && vv > bv) { bv = vv; bi = s; }
    }
#pragma unroll
    for (int o = 32; o >= 1; o >>= 1) {
      float ov = __shfl_xor(bv, o);
      int oi = __shfl_xor(bi, o);
      if (ov > bv || (ov == bv && oi < bi)) { bv = ov; bi = oi; }
    }
    pv = bv; pidx = bi;
    if (lane == 0) outp[k] = (bi == 0x7fffffff || bv == -INFINITY) ? 0 : bi;
  }
}

// ---------------------------------------------------------------------------
// Per-(b,t): gather + normalized gram + rel features + MLP + heads + softmax
// + bilinear palette blend -> V[b,t,:].
// ---------------------------------------------------------------------------
__global__ void __launch_bounds__(256) relmlp_kernel(
    const float* __restrict__ I, const float* __restrict__ P,
    const float* __restrict__ nI, const float* __restrict__ nP,
    const int* __restrict__ topk,
    const float* __restrict__ W1, const float* __restrict__ b1,
    const float* __restrict__ W2, const float* __restrict__ b2,
    const float* __restrict__ Wc, const float* __restrict__ bc,
    const float* __restrict__ Wm, const float* __restrict__ bm,
    const float* __restrict__ palT, float* __restrict__ V)
{
  const int row = blockIdx.x;
  const int t = row & (T_LEN - 1);
  const int base = row & ~(T_LEN - 1);
  const int nk = (t + 1 < KSEL) ? (t + 1) : KSEL;
  const int tid = threadIdx.x;

  __shared__ float vecS[16][516];
  __shared__ float gS[16][16];
  __shared__ float relS[KSEL][17];
  __shared__ float h1S[KSEL][HIDN];
  __shared__ float h2S[KSEL][HIDN];
  __shared__ float nrmS[16];
  __shared__ int   sidxS[16];
  __shared__ float mixS[KSEL], wS[KSEL], zxS[KSEL], zyS[KSEL];
  __shared__ float coefS[4 * KSEL];
  __shared__ int   cellS[4 * KSEL];

  if (tid < 16) {
    int s = t;
    if (tid >= 1) s = (tid <= nk) ? topk[(size_t)row * 16 + (tid - 1)] : 0;
    sidxS[tid] = s;
    nrmS[tid] = (tid == 0) ? nI[row] : nP[base + s];
  }
  __syncthreads();

  const int r = tid >> 4, c0 = tid & 15;
  const float* srcrow = (r == 0) ? (I + (size_t)row * D_DIM)
                                 : (P + ((size_t)base + sidxS[r]) * D_DIM);

  int pi = 0, pj = 0;
  {
    int p = tid;
    if (p < 136) {
      int i = 0;
      while (p >= 16 - i) { p -= 16 - i; ++i; }
      pi = i; pj = i + p;
    }
  }
  const bool pairOn = (tid < 136) && (pi <= nk) && (pj <= nk);
  float4 acc4 = make_float4(0.f, 0.f, 0.f, 0.f);

  for (int half = 0; half < 2; ++half) {
    if (half) __syncthreads();
    if (r <= nk) {
#pragma unroll
      for (int rep = 0; rep < 8; ++rep) {
        int q = c0 + 16 * rep;
        float4 v4 = *(const float4*)(srcrow + half * 512 + (q << 2));
        *(float4*)&vecS[r][q << 2] = v4;
      }
    }
    __syncthreads();
    if (pairOn) {
      const float4* va = (const float4*)&vecS[pi][0];
      const float4* vb = (const float4*)&vecS[pj][0];
#pragma unroll 4
      for (int q = 0; q < 128; ++q) {
        float4 a4 = va[q], b4 = vb[q];
        acc4.x = fmaf(a4.x, b4.x, acc4.x);
        acc4.y = fmaf(a4.y, b4.y, acc4.y);
        acc4.z = fmaf(a4.z, b4.z, acc4.z);
        acc4.w = fmaf(a4.w, b4.w, acc4.w);
      }
    }
  }
  if (tid < 136) {
    float g = 0.f;
    if (pairOn) {
      float acc = (acc4.x + acc4.y) + (acc4.z + acc4.w);
      g = acc / (nrmS[pi] * nrmS[pj]);
      g = fminf(fmaxf(g, -1.f), 1.f);
    }
    gS[pi][pj] = g;
    gS[pj][pi] = g;
  }
  __syncthreads();

  if (tid < KSEL * 17) {
    int k = tid / 17, f = tid % 17;
    float v = 0.f;
    if (k < nk) {
      if (f < KSEL)        v = (f < nk) ? gS[k + 1][f + 1] : 0.f;
      else if (f == KSEL)  v = gS[0][k + 1];
      else                 v = (float)(t - sidxS[k + 1]) * (1.0f / (float)T_LEN);
    }
    relS[k][f] = v;
  }
  __syncthreads();

  for (int o = tid; o < KSEL * HIDN; o += 256) {
    int k = o >> 6, m = o & 63;
    float a = b1[m];
#pragma unroll
    for (int f = 0; f < 17; ++f) a = fmaf(relS[k][f], W1[f * HIDN + m], a);
    h1S[k][m] = geluf(a);
  }
  __syncthreads();
  for (int o = tid; o < KSEL * HIDN; o += 256) {
    int k = o >> 6, m = o & 63;
    float a = b2[m];
#pragma unroll 8
    for (int n = 0; n < HIDN; ++n) a = fmaf(h1S[k][n], W2[n * HIDN + m], a);
    h2S[k][m] = geluf(a);
  }
  __syncthreads();
  if (tid < KSEL) {
    float a0 = 0.f, a1 = 0.f, am = 0.f;
#pragma unroll 8
    for (int n = 0; n < HIDN; ++n) {
      float h = h2S[tid][n];
      a0 = fmaf(h, Wc[n * 2 + 0], a0);
      a1 = fmaf(h, Wc[n * 2 + 1], a1);
      am = fmaf(h, Wm[n], am);
    }
    zxS[tid] = tanhf(a0 + bc[0]);
    zyS[tid] = tanhf(a1 + bc[1]);
    mixS[tid] = am + bm[0];
  }
  __syncthreads();
  if (tid == 0) {
    float mx = -INFINITY;
    for (int k = 0; k < nk; ++k) mx = fmaxf(mx, mixS[k]);
    float ssum = 0.f;
    for (int k = 0; k < nk; ++k) { float e = expf(mixS[k] - mx); wS[k] = e; ssum += e; }
    float inv = 1.f / ssum;
    for (int k = 0; k < nk; ++k) wS[k] *= inv;
  }
  __syncthreads();
  if (tid < KSEL) {
    int k = tid;
    if (k < nk) {
      float w = wS[k];
      float fx = fminf(fmaxf((zxS[k] + 1.f) * 0.5f * 15.f, 0.f), 15.f);
      float fy = fminf(fmaxf((zyS[k] + 1.f) * 0.5f * 15.f, 0.f), 15.f);
      int x0 = (int)floorf(fx); int x1i = (x0 + 1 < 15) ? x0 + 1 : 15;
      int y0 = (int)floorf(fy); int y1i = (y0 + 1 < 15) ? y0 + 1 : 15;
      float wx = fx - (float)x0, wy = fy - (float)y0;
      cellS[k * 4 + 0] = y0 * 16 + x0;   coefS[k * 4 + 0] = w * (1.f - wy) * (1.f - wx);
      cellS[k * 4 + 1] = y0 * 16 + x1i;  coefS[k * 4 + 1] = w * (1.f - wy) * wx;
      cellS[k * 4 + 2] = y1i * 16 + x0;  coefS[k * 4 + 2] = w * wy * (1.f - wx);
      cellS[k * 4 + 3] = y1i * 16 + x1i; coefS[k * 4 + 3] = w * wy * wx;
    } else {
      cellS[k * 4 + 0] = cellS[k * 4 + 1] = cellS[k * 4 + 2] = cellS[k * 4 + 3] = 0;
      coefS[k * 4 + 0] = coefS[k * 4 + 1] = coefS[k * 4 + 2] = coefS[k * 4 + 3] = 0.f;
    }
  }
  __syncthreads();
  const int nj = 4 * nk;
  for (int d = tid; d < D_DIM; d += 256) {
    float a = 0.f;
    for (int j = 0; j < nj; ++j)
      a = fmaf(coefS[j], palT[(size_t)cellS[j] * D_DIM + d], a);
    V[(size_t)row * D_DIM + d] = a;
  }
}

// ---------------------------------------------------------------------------
// Host launcher. Workspace (floats, ~65.3 MiB):
//   palT | I | P | S(32MB; trig table + V alias into it, all sequential) | norms | idx
// ---------------------------------------------------------------------------
extern "C" void kernel_launch(void* const* d_in, const int* in_sizes, int n_in,
                              void* d_out, int out_size, void* d_ws, size_t ws_size,
                              hipStream_t stream)
{
  (void)in_sizes; (void)n_in; (void)out_size; (void)ws_size;
  const float* x   = (const float*)d_in[0];
  const float* Wi  = (const float*)d_in[1];
  const float* Wp  = (const float*)d_in[2];
  const float* pal = (const float*)d_in[3];
  const float* W1  = (const float*)d_in[4];
  const float* b1  = (const float*)d_in[5];
  const float* W2  = (const float*)d_in[6];
  const float* b2  = (const float*)d_in[7];
  const float* Wc  = (const float*)d_in[8];
  const float* bc  = (const float*)d_in[9];
  const float* Wm  = (const float*)d_in[10];
  const float* bm  = (const float*)d_in[11];
  const float* Wo  = (const float*)d_in[12];
  float* out = (float*)d_out;

  float* w = (float*)d_ws;
  float* palT = w;  w += (size_t)256 * D_DIM;
  float* I    = w;  w += (size_t)BATCH * T_LEN * D_DIM;
  float* P    = w;  w += (size_t)BATCH * T_LEN * D_DIM;
  float* Sb   = w;  w += (size_t)BATCH * T_LEN * T_LEN;   // hosts tab & V sequentially
  float* nIb  = w;  w += (size_t)BATCH * T_LEN;
  float* nPb  = w;  w += (size_t)BATCH * T_LEN;
  int*   idx  = (int*)w;

  float2* tab = (float2*)Sb;   // consumed by rope BEFORE S is written
  float*  Vb  = Sb;            // V written AFTER topk consumed S

  const int MROWS = BATCH * T_LEN;  // 4096

  trig_table_kernel<<<T_LEN, 256, 0, stream>>>(tab);
  transpose_pal<<<dim3(256, 4), 256, 0, stream>>>(pal, palT);

  // I = x@Wi (z=0), P = x@Wp (z=1): one fused MFMA launch, 1024 blocks.
  gemm64q<false, false><<<dim3(D_DIM / 128, MROWS / 64, 2), 256, 0, stream>>>(
      x, Wi, Wp, I, D_DIM, D_DIM,
      0L, 0L, (long)MROWS * D_DIM, 1.0);

  rope_norm_kernel<<<MROWS, 256, 0, stream>>>(I, P, tab, nIb, nPb);

  // S[b] = (I_b @ P_b^T) * D^-0.5, packed causal grid (272 tiles/batch).
  gemm64q<true, true><<<dim3(272, 1, 2), 256, 0, stream>>>(
      I, P, P, Sb, T_LEN, D_DIM,
      (long)T_LEN * D_DIM, (long)T_LEN * D_DIM, (long)T_LEN * T_LEN, 0.03125);

  topk_kernel<<<dim3(T_LEN / 4, BATCH), 256, 0, stream>>>(Sb, idx);

  relmlp_kernel<<<MROWS, 256, 0, stream>>>(I, P, nIb, nPb, idx,
                                           W1, b1, W2, b2, Wc, bc, Wm, bm,
                                           palT, Vb);

  gemm128b<<<dim3(D_DIM / 128, MROWS / 64), 256, 0, stream>>>(
      Vb, Wo, out, MROWS, D_DIM, D_DIM, 1.0f);
}

// Round 10
// 817.783 us; speedup vs baseline: 2.5086x; 1.0812x over previous
//
#include <hip/hip_runtime.h>
#include <math.h>

// Problem constants (fixed by the reference)
#define BATCH 2
#define T_LEN 2048
#define D_DIM 1024
#define KSEL  15
#define HIDN  64

typedef double f64x4 __attribute__((ext_vector_type(4)));
typedef short  bf16x8 __attribute__((ext_vector_type(8)));
typedef float  f32x4v __attribute__((ext_vector_type(4)));

__device__ __forceinline__ float geluf(float x) {
  return 0.5f * x * (1.0f + erff(x * 0.70710678118654752440f));
}

__device__ __forceinline__ unsigned short f32_to_bf16_rne(float x) {
  unsigned u = __builtin_bit_cast(unsigned, x);
  unsigned lsb = (u >> 16) & 1u;
  u += 0x7fffu + lsb;
  return (unsigned short)(u >> 16);
}
__device__ __forceinline__ float bf16_to_f32(unsigned short h) {
  unsigned u = ((unsigned)h) << 16;
  return __builtin_bit_cast(float, u);
}

// ---------------------------------------------------------------------------
// f64 MFMA GEMM (f32 in / f32 out), v_mfma_f64_16x16x4_f64, LAYOUT-PROBED,
// 64x128 tile + LDS double-buffer + reg prefetch. (r9, unchanged — 70% MfmaUtil.)
// ---------------------------------------------------------------------------
template<bool BT, bool CAUSAL>
__global__ void __launch_bounds__(256, 3) gemm64q(
    const float* __restrict__ A, const float* __restrict__ Ba,
    const float* __restrict__ Bb, float* __restrict__ C,
    int N, int K, long sA, long sB, long sC, double alpha)
{
  int m0, n0;
  if (CAUSAL) {
    int rem = blockIdx.x, bi = 0;
    while (rem >= (bi >> 1) + 1) { rem -= (bi >> 1) + 1; ++bi; }
    m0 = bi << 6; n0 = rem << 7;
  } else {
    m0 = blockIdx.y << 6; n0 = blockIdx.x << 7;
  }
  const int z = blockIdx.z;
  A += (size_t)z * sA;
  const float* B = (z ? Bb : Ba) + (size_t)z * sB;
  C += (size_t)z * sC;

  const int tid = threadIdx.x;
  const int w = tid >> 6, lane = tid & 63;
  const int kl = lane >> 4, lm = lane & 15;
  const int am0 = (w & 1) << 5;
  const int bn0 = (w >> 1) << 6;

  __shared__ double As[2][16][66];
  __shared__ double Bs[2][16][130];

  // layout probe (buf 0)
  {
    int m = tid & 63, k4 = (tid >> 6) << 2;
#pragma unroll
    for (int q = 0; q < 4; ++q) As[0][k4 + q][m] = (double)m;
    int n = tid & 127, k8 = (tid >> 7) << 3;
#pragma unroll
    for (int q = 0; q < 8; ++q) Bs[0][k8 + q][n] = (double)n;
  }
  __syncthreads();
  int mr[4], nc[4];
  {
    double pa = As[0][kl][am0 + lm];
    double pb = Bs[0][kl][bn0 + lm];
    f64x4 d1 = {0.0, 0.0, 0.0, 0.0}, d2 = {0.0, 0.0, 0.0, 0.0};
    d1 = __builtin_amdgcn_mfma_f64_16x16x4f64(pa, 1.0, d1, 0, 0, 0);
    d2 = __builtin_amdgcn_mfma_f64_16x16x4f64(1.0, pb, d2, 0, 0, 0);
#pragma unroll
    for (int i = 0; i < 4; ++i) {
      mr[i] = ((int)d1[i]) >> 2;
      nc[i] = ((int)d2[i]) >> 2;
    }
  }
  __syncthreads();

  f64x4 c00 = {0,0,0,0}, c01 = {0,0,0,0}, c02 = {0,0,0,0}, c03 = {0,0,0,0};
  f64x4 c10 = {0,0,0,0}, c11 = {0,0,0,0}, c12 = {0,0,0,0}, c13 = {0,0,0,0};

  const int am = tid >> 2, akq = (tid & 3) << 2;
  const int bk = tid >> 4, bn8 = (tid & 15) << 3;
  const int tn = tid >> 1, tkq = (tid & 1) << 3;

  float4 ra, rb0, rb1;

  ra = *(const float4*)(A + (size_t)(m0 + am) * K + akq);
  if (!BT) {
    const float* bp = B + (size_t)bk * N + n0 + bn8;
    rb0 = *(const float4*)(bp); rb1 = *(const float4*)(bp + 4);
  } else {
    const float* bp = B + (size_t)(n0 + tn) * K + tkq;
    rb0 = *(const float4*)(bp); rb1 = *(const float4*)(bp + 4);
  }
  {
    As[0][akq + 0][am] = (double)ra.x; As[0][akq + 1][am] = (double)ra.y;
    As[0][akq + 2][am] = (double)ra.z; As[0][akq + 3][am] = (double)ra.w;
    if (!BT) {
      Bs[0][bk][bn8 + 0] = (double)rb0.x; Bs[0][bk][bn8 + 1] = (double)rb0.y;
      Bs[0][bk][bn8 + 2] = (double)rb0.z; Bs[0][bk][bn8 + 3] = (double)rb0.w;
      Bs[0][bk][bn8 + 4] = (double)rb1.x; Bs[0][bk][bn8 + 5] = (double)rb1.y;
      Bs[0][bk][bn8 + 6] = (double)rb1.z; Bs[0][bk][bn8 + 7] = (double)rb1.w;
    } else {
      Bs[0][tkq + 0][tn] = (double)rb0.x; Bs[0][tkq + 1][tn] = (double)rb0.y;
      Bs[0][tkq + 2][tn] = (double)rb0.z; Bs[0][tkq + 3][tn] = (double)rb0.w;
      Bs[0][tkq + 4][tn] = (double)rb1.x; Bs[0][tkq + 5][tn] = (double)rb1.y;
      Bs[0][tkq + 6][tn] = (double)rb1.z; Bs[0][tkq + 7][tn] = (double)rb1.w;
    }
  }
  __syncthreads();

  int buf = 0;
  for (int k0 = 0; k0 < K; k0 += 16) {
    const bool more = (k0 + 16) < K;
    if (more) {
      const int kn = k0 + 16;
      ra = *(const float4*)(A + (size_t)(m0 + am) * K + kn + akq);
      if (!BT) {
        const float* bp = B + (size_t)(kn + bk) * N + n0 + bn8;
        rb0 = *(const float4*)(bp); rb1 = *(const float4*)(bp + 4);
      } else {
        const float* bp = B + (size_t)(n0 + tn) * K + kn + tkq;
        rb0 = *(const float4*)(bp); rb1 = *(const float4*)(bp + 4);
      }
    }
#pragma unroll
    for (int ks = 0; ks < 4; ++ks) {
      const int kr = (ks << 2) + kl;
      double a0 = As[buf][kr][am0 + lm];
      double a1 = As[buf][kr][am0 + 16 + lm];
      double b0 = Bs[buf][kr][bn0 + lm];
      double b1 = Bs[buf][kr][bn0 + 16 + lm];
      double b2 = Bs[buf][kr][bn0 + 32 + lm];
      double b3 = Bs[buf][kr][bn0 + 48 + lm];
      c00 = __builtin_amdgcn_mfma_f64_16x16x4f64(a0, b0, c00, 0, 0, 0);
      c01 = __builtin_amdgcn_mfma_f64_16x16x4f64(a0, b1, c01, 0, 0, 0);
      c02 = __builtin_amdgcn_mfma_f64_16x16x4f64(a0, b2, c02, 0, 0, 0);
      c03 = __builtin_amdgcn_mfma_f64_16x16x4f64(a0, b3, c03, 0, 0, 0);
      c10 = __builtin_amdgcn_mfma_f64_16x16x4f64(a1, b0, c10, 0, 0, 0);
      c11 = __builtin_amdgcn_mfma_f64_16x16x4f64(a1, b1, c11, 0, 0, 0);
      c12 = __builtin_amdgcn_mfma_f64_16x16x4f64(a1, b2, c12, 0, 0, 0);
      c13 = __builtin_amdgcn_mfma_f64_16x16x4f64(a1, b3, c13, 0, 0, 0);
    }
    if (more) {
      const int nb = buf ^ 1;
      As[nb][akq + 0][am] = (double)ra.x; As[nb][akq + 1][am] = (double)ra.y;
      As[nb][akq + 2][am] = (double)ra.z; As[nb][akq + 3][am] = (double)ra.w;
      if (!BT) {
        Bs[nb][bk][bn8 + 0] = (double)rb0.x; Bs[nb][bk][bn8 + 1] = (double)rb0.y;
        Bs[nb][bk][bn8 + 2] = (double)rb0.z; Bs[nb][bk][bn8 + 3] = (double)rb0.w;
        Bs[nb][bk][bn8 + 4] = (double)rb1.x; Bs[nb][bk][bn8 + 5] = (double)rb1.y;
        Bs[nb][bk][bn8 + 6] = (double)rb1.z; Bs[nb][bk][bn8 + 7] = (double)rb1.w;
      } else {
        Bs[nb][tkq + 0][tn] = (double)rb0.x; Bs[nb][tkq + 1][tn] = (double)rb0.y;
        Bs[nb][tkq + 2][tn] = (double)rb0.z; Bs[nb][tkq + 3][tn] = (double)rb0.w;
        Bs[nb][tkq + 4][tn] = (double)rb1.x; Bs[nb][tkq + 5][tn] = (double)rb1.y;
        Bs[nb][tkq + 6][tn] = (double)rb1.z; Bs[nb][tkq + 7][tn] = (double)rb1.w;
      }
    }
    __syncthreads();
    buf ^= 1;
  }

#pragma unroll
  for (int i = 0; i < 4; ++i) {
    const size_t r0 = (size_t)(m0 + mr[i]) * N;
    const size_t r1 = r0 + (size_t)16 * N;
    const int c = n0 + nc[i];
    C[r0 + c +  0] = (float)(c00[i] * alpha);
    C[r0 + c + 16] = (float)(c01[i] * alpha);
    C[r0 + c + 32] = (float)(c02[i] * alpha);
    C[r0 + c + 48] = (float)(c03[i] * alpha);
    C[r1 + c +  0] = (float)(c10[i] * alpha);
    C[r1 + c + 16] = (float)(c11[i] * alpha);
    C[r1 + c + 32] = (float)(c12[i] * alpha);
    C[r1 + c + 48] = (float)(c13[i] * alpha);
  }
}

// ---------------------------------------------------------------------------
// Split f32 array into bf16 hi/lo planes (x ~= hi + lo, error ~2^-17 |x|).
// ---------------------------------------------------------------------------
__global__ void __launch_bounds__(256) split_bf16(const float* __restrict__ X,
                                                  unsigned short* __restrict__ H,
                                                  unsigned short* __restrict__ L)
{
  const int i = (blockIdx.x * 256 + threadIdx.x) * 4;
  float4 v = *(const float4*)(X + i);
  ushort4 h, l;
  h.x = f32_to_bf16_rne(v.x); l.x = f32_to_bf16_rne(v.x - bf16_to_f32(h.x));
  h.y = f32_to_bf16_rne(v.y); l.y = f32_to_bf16_rne(v.y - bf16_to_f32(h.y));
  h.z = f32_to_bf16_rne(v.z); l.z = f32_to_bf16_rne(v.z - bf16_to_f32(h.z));
  h.w = f32_to_bf16_rne(v.w); l.w = f32_to_bf16_rne(v.w - bf16_to_f32(h.w));
  *(ushort4*)(H + i) = h;
  *(ushort4*)(L + i) = l;
}

// ---------------------------------------------------------------------------
// Wo (K x N) -> transposed bf16 hi/lo planes (N x K), via LDS tile.
// ---------------------------------------------------------------------------
__global__ void __launch_bounds__(256) woconvT(const float* __restrict__ Wo,
                                               unsigned short* __restrict__ HT,
                                               unsigned short* __restrict__ LT)
{
  __shared__ float tile[64][65];
  const int k0 = blockIdx.y << 6, n0 = blockIdx.x << 6;
  const int tid = threadIdx.x;
  for (int idx = tid; idx < 4096; idx += 256) {
    int r = idx >> 6, c = idx & 63;
    tile[r][c] = Wo[(size_t)(k0 + r) * D_DIM + n0 + c];
  }
  __syncthreads();
  for (int idx = tid; idx < 4096; idx += 256) {
    int n = idx >> 6, k = idx & 63;
    float v = tile[k][n];
    unsigned short h = f32_to_bf16_rne(v);
    HT[(size_t)(n0 + n) * D_DIM + k0 + k] = h;
    LT[(size_t)(n0 + n) * D_DIM + k0 + k] = f32_to_bf16_rne(v - bf16_to_f32(h));
  }
}

// ---------------------------------------------------------------------------
// Split-bf16 MFMA GEMM for C = A @ B (f32-equivalent via hi/lo planes).
// A planes: M x K row-major. B planes: TRANSPOSED, N x K row-major.
// 64x128 tile, BK=32, 4 waves (each 32x64 = 2x4 MFMA 16x16x32 tiles),
// LDS dbuf + reg prefetch (gemm64q skeleton). Per tile: 3 MFMAs
// (ah*bh + ah*bl + al*bh); lo*lo omitted (~2^-18 rel). Output layout
// discovered by in-kernel probe (integer coords, bf16/f32-exact).
// Input k-maps: A and B fragments use the same (lane,slot)->k assumption;
// contraction is permutation-invariant, so any consistent bijection works.
// ---------------------------------------------------------------------------
__global__ void __launch_bounds__(256) gemmbf(
    const unsigned short* __restrict__ Ah, const unsigned short* __restrict__ Al,
    const unsigned short* __restrict__ BhT, const unsigned short* __restrict__ BlT,
    float* __restrict__ C, int N, int K)
{
  const int m0 = blockIdx.y << 6, n0 = blockIdx.x << 7;
  const int tid = threadIdx.x;
  const int w = tid >> 6, lane = tid & 63;
  const int kg = lane >> 4, lm = lane & 15;
  const int am0 = (w & 1) << 5;
  const int bn0 = (w >> 1) << 6;

  __shared__ unsigned short As_h[2][64][40],  As_l[2][64][40];
  __shared__ unsigned short Bs_h[2][128][40], Bs_l[2][128][40];

  bf16x8 ones;
#pragma unroll
  for (int e = 0; e < 8; ++e) ones[e] = (short)0x3F80;

  // ---------------- layout probe (buf 0, h-planes) ----------------
  for (int idx = tid; idx < 2048; idx += 256)
    As_h[0][idx >> 5][idx & 31] = f32_to_bf16_rne((float)(idx >> 5));
  for (int idx = tid; idx < 4096; idx += 256)
    Bs_h[0][idx >> 5][idx & 31] = f32_to_bf16_rne((float)(idx >> 5));
  __syncthreads();
  int mr[4], nc[4];
  {
    bf16x8 pa = *(const bf16x8*)&As_h[0][am0 + lm][kg << 3];
    bf16x8 pb = *(const bf16x8*)&Bs_h[0][bn0 + lm][kg << 3];
    f32x4v d1 = {0.f, 0.f, 0.f, 0.f}, d2 = {0.f, 0.f, 0.f, 0.f};
    d1 = __builtin_amdgcn_mfma_f32_16x16x32_bf16(pa, ones, d1, 0, 0, 0);
    d2 = __builtin_amdgcn_mfma_f32_16x16x32_bf16(ones, pb, d2, 0, 0, 0);
#pragma unroll
    for (int e = 0; e < 4; ++e) {
      mr[e] = ((int)d1[e]) >> 5;   // D = 32*row (exact)
      nc[e] = ((int)d2[e]) >> 5;   // D = 32*col (exact)
    }
  }
  __syncthreads();

  f32x4v c00 = {0,0,0,0}, c01 = {0,0,0,0}, c02 = {0,0,0,0}, c03 = {0,0,0,0};
  f32x4v c10 = {0,0,0,0}, c11 = {0,0,0,0}, c12 = {0,0,0,0}, c13 = {0,0,0,0};

  // staging ownership: A 64x32 ushorts = 256 chunks of 8; B 128x32 = 512 chunks
  const int ar  = tid >> 2, ak8 = (tid & 3) << 3;
  const int bna = tid >> 2, bnb = 64 + (tid >> 2), bk8 = (tid & 3) << 3;

  bf16x8 rah, ral, rbh0, rbl0, rbh1, rbl1;

  // prologue: k0 = 0 -> buf 0
  rah  = *(const bf16x8*)(Ah  + (size_t)(m0 + ar) * K + ak8);
  ral  = *(const bf16x8*)(Al  + (size_t)(m0 + ar) * K + ak8);
  rbh0 = *(const bf16x8*)(BhT + (size_t)(n0 + bna) * K + bk8);
  rbl0 = *(const bf16x8*)(BlT + (size_t)(n0 + bna) * K + bk8);
  rbh1 = *(const bf16x8*)(BhT + (size_t)(n0 + bnb) * K + bk8);
  rbl1 = *(const bf16x8*)(BlT + (size_t)(n0 + bnb) * K + bk8);
  *(bf16x8*)&As_h[0][ar][ak8]  = rah;
  *(bf16x8*)&As_l[0][ar][ak8]  = ral;
  *(bf16x8*)&Bs_h[0][bna][bk8] = rbh0;
  *(bf16x8*)&Bs_l[0][bna][bk8] = rbl0;
  *(bf16x8*)&Bs_h[0][bnb][bk8] = rbh1;
  *(bf16x8*)&Bs_l[0][bnb][bk8] = rbl1;
  __syncthreads();

  int buf = 0;
  for (int k0 = 0; k0 < K; k0 += 32) {
    const bool more = (k0 + 32) < K;
    if (more) {
      const int kn = k0 + 32;
      rah  = *(const bf16x8*)(Ah  + (size_t)(m0 + ar) * K + kn + ak8);
      ral  = *(const bf16x8*)(Al  + (size_t)(m0 + ar) * K + kn + ak8);
      rbh0 = *(const bf16x8*)(BhT + (size_t)(n0 + bna) * K + kn + bk8);
      rbl0 = *(const bf16x8*)(BlT + (size_t)(n0 + bna) * K + kn + bk8);
      rbh1 = *(const bf16x8*)(BhT + (size_t)(n0 + bnb) * K + kn + bk8);
      rbl1 = *(const bf16x8*)(BlT + (size_t)(n0 + bnb) * K + kn + bk8);
    }
    {
      bf16x8 ah0 = *(const bf16x8*)&As_h[buf][am0 + lm][kg << 3];
      bf16x8 ah1 = *(const bf16x8*)&As_h[buf][am0 + 16 + lm][kg << 3];
      bf16x8 al0 = *(const bf16x8*)&As_l[buf][am0 + lm][kg << 3];
      bf16x8 al1 = *(const bf16x8*)&As_l[buf][am0 + 16 + lm][kg << 3];
      bf16x8 bh0 = *(const bf16x8*)&Bs_h[buf][bn0 + lm][kg << 3];
      bf16x8 bh1 = *(const bf16x8*)&Bs_h[buf][bn0 + 16 + lm][kg << 3];
      bf16x8 bh2 = *(const bf16x8*)&Bs_h[buf][bn0 + 32 + lm][kg << 3];
      bf16x8 bh3 = *(const bf16x8*)&Bs_h[buf][bn0 + 48 + lm][kg << 3];
      bf16x8 bl0 = *(const bf16x8*)&Bs_l[buf][bn0 + lm][kg << 3];
      bf16x8 bl1 = *(const bf16x8*)&Bs_l[buf][bn0 + 16 + lm][kg << 3];
      bf16x8 bl2 = *(const bf16x8*)&Bs_l[buf][bn0 + 32 + lm][kg << 3];
      bf16x8 bl3 = *(const bf16x8*)&Bs_l[buf][bn0 + 48 + lm][kg << 3];

      c00 = __builtin_amdgcn_mfma_f32_16x16x32_bf16(ah0, bh0, c00, 0, 0, 0);
      c01 = __builtin_amdgcn_mfma_f32_16x16x32_bf16(ah0, bh1, c01, 0, 0, 0);
      c02 = __builtin_amdgcn_mfma_f32_16x16x32_bf16(ah0, bh2, c02, 0, 0, 0);
      c03 = __builtin_amdgcn_mfma_f32_16x16x32_bf16(ah0, bh3, c03, 0, 0, 0);
      c10 = __builtin_amdgcn_mfma_f32_16x16x32_bf16(ah1, bh0, c10, 0, 0, 0);
      c11 = __builtin_amdgcn_mfma_f32_16x16x32_bf16(ah1, bh1, c11, 0, 0, 0);
      c12 = __builtin_amdgcn_mfma_f32_16x16x32_bf16(ah1, bh2, c12, 0, 0, 0);
      c13 = __builtin_amdgcn_mfma_f32_16x16x32_bf16(ah1, bh3, c13, 0, 0, 0);

      c00 = __builtin_amdgcn_mfma_f32_16x16x32_bf16(ah0, bl0, c00, 0, 0, 0);
      c01 = __builtin_amdgcn_mfma_f32_16x16x32_bf16(ah0, bl1, c01, 0, 0, 0);
      c02 = __builtin_amdgcn_mfma_f32_16x16x32_bf16(ah0, bl2, c02, 0, 0, 0);
      c03 = __builtin_amdgcn_mfma_f32_16x16x32_bf16(ah0, bl3, c03, 0, 0, 0);
      c10 = __builtin_amdgcn_mfma_f32_16x16x32_bf16(ah1, bl0, c10, 0, 0, 0);
      c11 = __builtin_amdgcn_mfma_f32_16x16x32_bf16(ah1, bl1, c11, 0, 0, 0);
      c12 = __builtin_amdgcn_mfma_f32_16x16x32_bf16(ah1, bl2, c12, 0, 0, 0);
      c13 = __builtin_amdgcn_mfma_f32_16x16x32_bf16(ah1, bl3, c13, 0, 0, 0);

      c00 = __builtin_amdgcn_mfma_f32_16x16x32_bf16(al0, bh0, c00, 0, 0, 0);
      c01 = __builtin_amdgcn_mfma_f32_16x16x32_bf16(al0, bh1, c01, 0, 0, 0);
      c02 = __builtin_amdgcn_mfma_f32_16x16x32_bf16(al0, bh2, c02, 0, 0, 0);
      c03 = __builtin_amdgcn_mfma_f32_16x16x32_bf16(al0, bh3, c03, 0, 0, 0);
      c10 = __builtin_amdgcn_mfma_f32_16x16x32_bf16(al1, bh0, c10, 0, 0, 0);
      c11 = __builtin_amdgcn_mfma_f32_16x16x32_bf16(al1, bh1, c11, 0, 0, 0);
      c12 = __builtin_amdgcn_mfma_f32_16x16x32_bf16(al1, bh2, c12, 0, 0, 0);
      c13 = __builtin_amdgcn_mfma_f32_16x16x32_bf16(al1, bh3, c13, 0, 0, 0);
    }
    if (more) {
      const int nb = buf ^ 1;
      *(bf16x8*)&As_h[nb][ar][ak8]  = rah;
      *(bf16x8*)&As_l[nb][ar][ak8]  = ral;
      *(bf16x8*)&Bs_h[nb][bna][bk8] = rbh0;
      *(bf16x8*)&Bs_l[nb][bna][bk8] = rbl0;
      *(bf16x8*)&Bs_h[nb][bnb][bk8] = rbh1;
      *(bf16x8*)&Bs_l[nb][bnb][bk8] = rbl1;
    }
    __syncthreads();
    buf ^= 1;
  }

  // C-write via probed mapping (row-tile +16, col-tiles +16j by linearity)
#pragma unroll
  for (int e = 0; e < 4; ++e) {
    const size_t r0 = (size_t)(m0 + mr[e]) * N;
    const size_t r1 = r0 + (size_t)16 * N;
    const int c = n0 + nc[e];
    C[r0 + c +  0] = c00[e];
    C[r0 + c + 16] = c01[e];
    C[r0 + c + 32] = c02[e];
    C[r0 + c + 48] = c03[e];
    C[r1 + c +  0] = c10[e];
    C[r1 + c + 16] = c11[e];
    C[r1 + c + 32] = c12[e];
    C[r1 + c + 48] = c13[e];
  }
}

// ---------------------------------------------------------------------------
// Trig table: EXACT reference f32 bits. DO NOT change — selection-critical.
// ---------------------------------------------------------------------------
__global__ void __launch_bounds__(256) trig_table_kernel(float2* __restrict__ tab)
{
  const int t = blockIdx.x;
  for (int j = threadIdx.x; j < 512; j += 256) {
    double e = (double)j * (1.0 / 512.0);
    float pf = (float)pow(10000.0, e);
    float invf = 1.0f / pf;
    float angf = (float)t * invf;
    double s64, c64;
    sincos((double)angf, &s64, &c64);
    tab[(size_t)t * 512 + j] = make_float2((float)c64, (float)s64);
  }
}

// ---------------------------------------------------------------------------
// RoPE in place + row L2 norms. DO NOT change — selection-critical.
// ---------------------------------------------------------------------------
__global__ void __launch_bounds__(256) rope_norm_kernel(float* __restrict__ bI,
                                                        float* __restrict__ bP,
                                                        const float2* __restrict__ tab,
                                                        float* __restrict__ nI,
                                                        float* __restrict__ nP)
{
  const int row = blockIdx.x;
  const int t = row & (T_LEN - 1);
  const int tid = threadIdx.x;
  __shared__ double redI[4], redP[4];
  double ssI = 0.0, ssP = 0.0;
  const size_t off = (size_t)row * D_DIM;
  for (int j = tid; j < 512; j += 256) {
    float2 cs = tab[(size_t)t * 512 + j];
    float c = cs.x, s = cs.y;

    float a1 = bI[off + j], a2 = bI[off + 512 + j];
    float o1 = __fsub_rn(__fmul_rn(a1, c), __fmul_rn(a2, s));
    float o2 = __fadd_rn(__fmul_rn(a1, s), __fmul_rn(a2, c));
    bI[off + j] = o1; bI[off + 512 + j] = o2;
    ssI += (double)o1 * o1 + (double)o2 * o2;

    float p1 = bP[off + j], p2 = bP[off + 512 + j];
    float q1 = __fsub_rn(__fmul_rn(p1, c), __fmul_rn(p2, s));
    float q2 = __fadd_rn(__fmul_rn(p1, s), __fmul_rn(p2, c));
    bP[off + j] = q1; bP[off + 512 + j] = q2;
    ssP += (double)q1 * q1 + (double)q2 * q2;
  }
#pragma unroll
  for (int o = 32; o >= 1; o >>= 1) { ssI += __shfl_xor(ssI, o); ssP += __shfl_xor(ssP, o); }
  if ((tid & 63) == 0) { redI[tid >> 6] = ssI; redP[tid >> 6] = ssP; }
  __syncthreads();
  if (tid == 0) {
    nI[row] = fmaxf((float)sqrt(redI[0] + redI[1] + redI[2] + redI[3]), 1e-12f);
    nP[row] = fmaxf((float)sqrt(redP[0] + redP[1] + redP[2] + redP[3]), 1e-12f);
  }
}

// ---------------------------------------------------------------------------
// palette (D x 256) -> palT (256 x D)
// ---------------------------------------------------------------------------
__global__ void transpose_pal(const float* __restrict__ pal, float* __restrict__ palT)
{
  int c = blockIdx.x;
  int d = blockIdx.y * 256 + threadIdx.x;
  palT[(size_t)c * D_DIM + d] = pal[(size_t)d * 256 + c];
}

// ---------------------------------------------------------------------------
// Top-15 per causal row, both batches. One wave per row.
// ---------------------------------------------------------------------------
__global__ void __launch_bounds__(256) topk_kernel(const float* __restrict__ Sb,
                                                   int* __restrict__ idx)
{
  const int b = blockIdx.y;
  const float* S = Sb + (size_t)b * T_LEN * T_LEN;
  const int wave = threadIdx.x >> 6, lane = threadIdx.x & 63;
  const int t = blockIdx.x * 4 + wave;
  const float* rowp = S + (size_t)t * T_LEN;
  float v[32];
#pragma unroll
  for (int i = 0; i < 32; ++i) {
    int s = lane + (i << 6);
    v[i] = (s <= t) ? rowp[s] : -INFINITY;
  }
  float pv = INFINITY; int pidx = -1;
  int* outp = idx + ((size_t)b * T_LEN + t) * 16;
  for (int k = 0; k < KSEL; ++k) {
    float bv = -INFINITY; int bi = 0x7fffffff;
#pragma unroll
    for (int i = 0; i < 32; ++i) {
      int s = lane + (i << 6);
      float vv = v[i];
      bool elig = (vv < pv) || (vv == pv && s > pidx);
      if (elig && vv > bv) { bv = vv; bi = s; }
    }
#pragma unroll
    for (int o = 32; o >= 1; o >>= 1) {
      float ov = __shfl_xor(bv, o);
      int oi = __shfl_xor(bi, o);
      if (ov > bv || (ov == bv && oi < bi)) { bv = ov; bi = oi; }
    }
    pv = bv; pidx = bi;
    if (lane == 0) outp[k] = (bi == 0x7fffffff || bv == -INFINITY) ? 0 : bi;
  }
}

// ---------------------------------------------------------------------------
// Per-(b,t): gather + normalized gram + rel features + MLP + heads + softmax
// + bilinear palette blend -> V[b,t,:].
// ---------------------------------------------------------------------------
__global__ void __launch_bounds__(256) relmlp_kernel(
    const float* __restrict__ I, const float* __restrict__ P,
    const float* __restrict__ nI, const float* __restrict__ nP,
    const int* __restrict__ topk,
    const float* __restrict__ W1, const float* __restrict__ b1,
    const float* __restrict__ W2, const float* __restrict__ b2,
    const float* __restrict__ Wc, const float* __restrict__ bc,
    const float* __restrict__ Wm, const float* __restrict__ bm,
    const float* __restrict__ palT, float* __restrict__ V)
{
  const int row = blockIdx.x;
  const int t = row & (T_LEN - 1);
  const int base = row & ~(T_LEN - 1);
  const int nk = (t + 1 < KSEL) ? (t + 1) : KSEL;
  const int tid = threadIdx.x;

  __shared__ float vecS[16][516];
  __shared__ float gS[16][16];
  __shared__ float relS[KSEL][17];
  __shared__ float h1S[KSEL][HIDN];
  __shared__ float h2S[KSEL][HIDN];
  __shared__ float nrmS[16];
  __shared__ int   sidxS[16];
  __shared__ float mixS[KSEL], wS[KSEL], zxS[KSEL], zyS[KSEL];
  __shared__ float coefS[4 * KSEL];
  __shared__ int   cellS[4 * KSEL];

  if (tid < 16) {
    int s = t;
    if (tid >= 1) s = (tid <= nk) ? topk[(size_t)row * 16 + (tid - 1)] : 0;
    sidxS[tid] = s;
    nrmS[tid] = (tid == 0) ? nI[row] : nP[base + s];
  }
  __syncthreads();

  const int r = tid >> 4, c0 = tid & 15;
  const float* srcrow = (r == 0) ? (I + (size_t)row * D_DIM)
                                 : (P + ((size_t)base + sidxS[r]) * D_DIM);

  int pi = 0, pj = 0;
  {
    int p = tid;
    if (p < 136) {
      int i = 0;
      while (p >= 16 - i) { p -= 16 - i; ++i; }
      pi = i; pj = i + p;
    }
  }
  const bool pairOn = (tid < 136) && (pi <= nk) && (pj <= nk);
  float4 acc4 = make_float4(0.f, 0.f, 0.f, 0.f);

  for (int half = 0; half < 2; ++half) {
    if (half) __syncthreads();
    if (r <= nk) {
#pragma unroll
      for (int rep = 0; rep < 8; ++rep) {
        int q = c0 + 16 * rep;
        float4 v4 = *(const float4*)(srcrow + half * 512 + (q << 2));
        *(float4*)&vecS[r][q << 2] = v4;
      }
    }
    __syncthreads();
    if (pairOn) {
      const float4* va = (const float4*)&vecS[pi][0];
      const float4* vb = (const float4*)&vecS[pj][0];
#pragma unroll 4
      for (int q = 0; q < 128; ++q) {
        float4 a4 = va[q], b4 = vb[q];
        acc4.x = fmaf(a4.x, b4.x, acc4.x);
        acc4.y = fmaf(a4.y, b4.y, acc4.y);
        acc4.z = fmaf(a4.z, b4.z, acc4.z);
        acc4.w = fmaf(a4.w, b4.w, acc4.w);
      }
    }
  }
  if (tid < 136) {
    float g = 0.f;
    if (pairOn) {
      float acc = (acc4.x + acc4.y) + (acc4.z + acc4.w);
      g = acc / (nrmS[pi] * nrmS[pj]);
      g = fminf(fmaxf(g, -1.f), 1.f);
    }
    gS[pi][pj] = g;
    gS[pj][pi] = g;
  }
  __syncthreads();

  if (tid < KSEL * 17) {
    int k = tid / 17, f = tid % 17;
    float v = 0.f;
    if (k < nk) {
      if (f < KSEL)        v = (f < nk) ? gS[k + 1][f + 1] : 0.f;
      else if (f == KSEL)  v = gS[0][k + 1];
      else                 v = (float)(t - sidxS[k + 1]) * (1.0f / (float)T_LEN);
    }
    relS[k][f] = v;
  }
  __syncthreads();

  for (int o = tid; o < KSEL * HIDN; o += 256) {
    int k = o >> 6, m = o & 63;
    float a = b1[m];
#pragma unroll
    for (int f = 0; f < 17; ++f) a = fmaf(relS[k][f], W1[f * HIDN + m], a);
    h1S[k][m] = geluf(a);
  }
  __syncthreads();
  for (int o = tid; o < KSEL * HIDN; o += 256) {
    int k = o >> 6, m = o & 63;
    float a = b2[m];
#pragma unroll 8
    for (int n = 0; n < HIDN; ++n) a = fmaf(h1S[k][n], W2[n * HIDN + m], a);
    h2S[k][m] = geluf(a);
  }
  __syncthreads();
  if (tid < KSEL) {
    float a0 = 0.f, a1 = 0.f, am = 0.f;
#pragma unroll 8
    for (int n = 0; n < HIDN; ++n) {
      float h = h2S[tid][n];
      a0 = fmaf(h, Wc[n * 2 + 0], a0);
      a1 = fmaf(h, Wc[n * 2 + 1], a1);
      am = fmaf(h, Wm[n], am);
    }
    zxS[tid] = tanhf(a0 + bc[0]);
    zyS[tid] = tanhf(a1 + bc[1]);
    mixS[tid] = am + bm[0];
  }
  __syncthreads();
  if (tid == 0) {
    float mx = -INFINITY;
    for (int k = 0; k < nk; ++k) mx = fmaxf(mx, mixS[k]);
    float ssum = 0.f;
    for (int k = 0; k < nk; ++k) { float e = expf(mixS[k] - mx); wS[k] = e; ssum += e; }
    float inv = 1.f / ssum;
    for (int k = 0; k < nk; ++k) wS[k] *= inv;
  }
  __syncthreads();
  if (tid < KSEL) {
    int k = tid;
    if (k < nk) {
      float w = wS[k];
      float fx = fminf(fmaxf((zxS[k] + 1.f) * 0.5f * 15.f, 0.f), 15.f);
      float fy = fminf(fmaxf((zyS[k] + 1.f) * 0.5f * 15.f, 0.f), 15.f);
      int x0 = (int)floorf(fx); int x1i = (x0 + 1 < 15) ? x0 + 1 : 15;
      int y0 = (int)floorf(fy); int y1i = (y0 + 1 < 15) ? y0 + 1 : 15;
      float wx = fx - (float)x0, wy = fy - (float)y0;
      cellS[k * 4 + 0] = y0 * 16 + x0;   coefS[k * 4 + 0] = w * (1.f - wy) * (1.f - wx);
      cellS[k * 4 + 1] = y0 * 16 + x1i;  coefS[k * 4 + 1] = w * (1.f - wy) * wx;
      cellS[k * 4 + 2] = y1i * 16 + x0;  coefS[k * 4 + 2] = w * wy * (1.f - wx);
      cellS[k * 4 + 3] = y1i * 16 + x1i; coefS[k * 4 + 3] = w * wy * wx;
    } else {
      cellS[k * 4 + 0] = cellS[k * 4 + 1] = cellS[k * 4 + 2] = cellS[k * 4 + 3] = 0;
      coefS[k * 4 + 0] = coefS[k * 4 + 1] = coefS[k * 4 + 2] = coefS[k * 4 + 3] = 0.f;
    }
  }
  __syncthreads();
  const int nj = 4 * nk;
  for (int d = tid; d < D_DIM; d += 256) {
    float a = 0.f;
    for (int j = 0; j < nj; ++j)
      a = fmaf(coefS[j], palT[(size_t)cellS[j] * D_DIM + d], a);
    V[(size_t)row * D_DIM + d] = a;
  }
}

// ---------------------------------------------------------------------------
// Host launcher. Workspace reuse: S buffer (32MB) hosts tab (pre-S), then
// V (first 16MB) + V bf16 planes (second 16MB); P hosts Wo bf16 planes
// after relmlp (P dead).
// ---------------------------------------------------------------------------
extern "C" void kernel_launch(void* const* d_in, const int* in_sizes, int n_in,
                              void* d_out, int out_size, void* d_ws, size_t ws_size,
                              hipStream_t stream)
{
  (void)in_sizes; (void)n_in; (void)out_size; (void)ws_size;
  const float* x   = (const float*)d_in[0];
  const float* Wi  = (const float*)d_in[1];
  const float* Wp  = (const float*)d_in[2];
  const float* pal = (const float*)d_in[3];
  const float* W1  = (const float*)d_in[4];
  const float* b1  = (const float*)d_in[5];
  const float* W2  = (const float*)d_in[6];
  const float* b2  = (const float*)d_in[7];
  const float* Wc  = (const float*)d_in[8];
  const float* bc  = (const float*)d_in[9];
  const float* Wm  = (const float*)d_in[10];
  const float* bm  = (const float*)d_in[11];
  const float* Wo  = (const float*)d_in[12];
  float* out = (float*)d_out;

  float* w = (float*)d_ws;
  float* palT = w;  w += (size_t)256 * D_DIM;
  float* I    = w;  w += (size_t)BATCH * T_LEN * D_DIM;
  float* P    = w;  w += (size_t)BATCH * T_LEN * D_DIM;
  float* Sb   = w;  w += (size_t)BATCH * T_LEN * T_LEN;
  float* nIb  = w;  w += (size_t)BATCH * T_LEN;
  float* nPb  = w;  w += (size_t)BATCH * T_LEN;
  int*   idx  = (int*)w;

  float2* tab = (float2*)Sb;                     // pre-S
  float*  Vb  = Sb;                              // post-topk, first 16MB
  unsigned short* Vh = (unsigned short*)(Sb + (size_t)4 * 1024 * 1024);  // +16MB
  unsigned short* Vl = Vh + (size_t)4 * 1024 * 1024;                     // +24MB
  unsigned short* WohT = (unsigned short*)P;     // P dead after relmlp
  unsigned short* WolT = WohT + (size_t)D_DIM * D_DIM;

  const int MROWS = BATCH * T_LEN;  // 4096

  trig_table_kernel<<<T_LEN, 256, 0, stream>>>(tab);
  transpose_pal<<<dim3(256, 4), 256, 0, stream>>>(pal, palT);

  gemm64q<false, false><<<dim3(D_DIM / 128, MROWS / 64, 2), 256, 0, stream>>>(
      x, Wi, Wp, I, D_DIM, D_DIM,
      0L, 0L, (long)MROWS * D_DIM, 1.0);

  rope_norm_kernel<<<MROWS, 256, 0, stream>>>(I, P, tab, nIb, nPb);

  gemm64q<true, true><<<dim3(272, 1, 2), 256, 0, stream>>>(
      I, P, P, Sb, T_LEN, D_DIM,
      (long)T_LEN * D_DIM, (long)T_LEN * D_DIM, (long)T_LEN * T_LEN, 0.03125);

  topk_kernel<<<dim3(T_LEN / 4, BATCH), 256, 0, stream>>>(Sb, idx);

  relmlp_kernel<<<MROWS, 256, 0, stream>>>(I, P, nIb, nPb, idx,
                                           W1, b1, W2, b2, Wc, bc, Wm, bm,
                                           palT, Vb);

  // V @ Wo via split-bf16 MFMA
  split_bf16<<<(MROWS * D_DIM) / (256 * 4), 256, 0, stream>>>(Vb, Vh, Vl);
  woconvT<<<dim3(D_DIM / 64, D_DIM / 64), 256, 0, stream>>>(Wo, WohT, WolT);
  gemmbf<<<dim3(D_DIM / 128, MROWS / 64), 256, 0, stream>>>(
      Vh, Vl, WohT, WolT, out, D_DIM, D_DIM);
}

// Round 11
// 735.648 us; speedup vs baseline: 2.7886x; 1.1116x over previous
//
#include <hip/hip_runtime.h>
#include <math.h>

// Problem constants (fixed by the reference)
#define BATCH 2
#define T_LEN 2048
#define D_DIM 1024
#define KSEL  15
#define HIDN  64
#define NCAND 20

typedef double f64x4 __attribute__((ext_vector_type(4)));
typedef short  bf16x8 __attribute__((ext_vector_type(8)));
typedef float  f32x4v __attribute__((ext_vector_type(4)));

__device__ __forceinline__ float geluf(float x) {
  return 0.5f * x * (1.0f + erff(x * 0.70710678118654752440f));
}

__device__ __forceinline__ unsigned short f32_to_bf16_rne(float x) {
  unsigned u = __builtin_bit_cast(unsigned, x);
  unsigned lsb = (u >> 16) & 1u;
  u += 0x7fffu + lsb;
  return (unsigned short)(u >> 16);
}
__device__ __forceinline__ float bf16_to_f32(unsigned short h) {
  unsigned u = ((unsigned)h) << 16;
  return __builtin_bit_cast(float, u);
}

// ---------------------------------------------------------------------------
// f64 MFMA GEMM (f32 in / f32 out), v_mfma_f64_16x16x4_f64, LAYOUT-PROBED,
// 64x128 tile + LDS double-buffer + reg prefetch. (r9/r10, unchanged.)
// Used ONLY for x@Wi / x@Wp now (selection-critical values).
// ---------------------------------------------------------------------------
template<bool BT, bool CAUSAL>
__global__ void __launch_bounds__(256, 3) gemm64q(
    const float* __restrict__ A, const float* __restrict__ Ba,
    const float* __restrict__ Bb, float* __restrict__ C,
    int N, int K, long sA, long sB, long sC, double alpha)
{
  int m0, n0;
  if (CAUSAL) {
    int rem = blockIdx.x, bi = 0;
    while (rem >= (bi >> 1) + 1) { rem -= (bi >> 1) + 1; ++bi; }
    m0 = bi << 6; n0 = rem << 7;
  } else {
    m0 = blockIdx.y << 6; n0 = blockIdx.x << 7;
  }
  const int z = blockIdx.z;
  A += (size_t)z * sA;
  const float* B = (z ? Bb : Ba) + (size_t)z * sB;
  C += (size_t)z * sC;

  const int tid = threadIdx.x;
  const int w = tid >> 6, lane = tid & 63;
  const int kl = lane >> 4, lm = lane & 15;
  const int am0 = (w & 1) << 5;
  const int bn0 = (w >> 1) << 6;

  __shared__ double As[2][16][66];
  __shared__ double Bs[2][16][130];

  // layout probe (buf 0)
  {
    int m = tid & 63, k4 = (tid >> 6) << 2;
#pragma unroll
    for (int q = 0; q < 4; ++q) As[0][k4 + q][m] = (double)m;
    int n = tid & 127, k8 = (tid >> 7) << 3;
#pragma unroll
    for (int q = 0; q < 8; ++q) Bs[0][k8 + q][n] = (double)n;
  }
  __syncthreads();
  int mr[4], nc[4];
  {
    double pa = As[0][kl][am0 + lm];
    double pb = Bs[0][kl][bn0 + lm];
    f64x4 d1 = {0.0, 0.0, 0.0, 0.0}, d2 = {0.0, 0.0, 0.0, 0.0};
    d1 = __builtin_amdgcn_mfma_f64_16x16x4f64(pa, 1.0, d1, 0, 0, 0);
    d2 = __builtin_amdgcn_mfma_f64_16x16x4f64(1.0, pb, d2, 0, 0, 0);
#pragma unroll
    for (int i = 0; i < 4; ++i) {
      mr[i] = ((int)d1[i]) >> 2;
      nc[i] = ((int)d2[i]) >> 2;
    }
  }
  __syncthreads();

  f64x4 c00 = {0,0,0,0}, c01 = {0,0,0,0}, c02 = {0,0,0,0}, c03 = {0,0,0,0};
  f64x4 c10 = {0,0,0,0}, c11 = {0,0,0,0}, c12 = {0,0,0,0}, c13 = {0,0,0,0};

  const int am = tid >> 2, akq = (tid & 3) << 2;
  const int bk = tid >> 4, bn8 = (tid & 15) << 3;
  const int tn = tid >> 1, tkq = (tid & 1) << 3;

  float4 ra, rb0, rb1;

  ra = *(const float4*)(A + (size_t)(m0 + am) * K + akq);
  if (!BT) {
    const float* bp = B + (size_t)bk * N + n0 + bn8;
    rb0 = *(const float4*)(bp); rb1 = *(const float4*)(bp + 4);
  } else {
    const float* bp = B + (size_t)(n0 + tn) * K + tkq;
    rb0 = *(const float4*)(bp); rb1 = *(const float4*)(bp + 4);
  }
  {
    As[0][akq + 0][am] = (double)ra.x; As[0][akq + 1][am] = (double)ra.y;
    As[0][akq + 2][am] = (double)ra.z; As[0][akq + 3][am] = (double)ra.w;
    if (!BT) {
      Bs[0][bk][bn8 + 0] = (double)rb0.x; Bs[0][bk][bn8 + 1] = (double)rb0.y;
      Bs[0][bk][bn8 + 2] = (double)rb0.z; Bs[0][bk][bn8 + 3] = (double)rb0.w;
      Bs[0][bk][bn8 + 4] = (double)rb1.x; Bs[0][bk][bn8 + 5] = (double)rb1.y;
      Bs[0][bk][bn8 + 6] = (double)rb1.z; Bs[0][bk][bn8 + 7] = (double)rb1.w;
    } else {
      Bs[0][tkq + 0][tn] = (double)rb0.x; Bs[0][tkq + 1][tn] = (double)rb0.y;
      Bs[0][tkq + 2][tn] = (double)rb0.z; Bs[0][tkq + 3][tn] = (double)rb0.w;
      Bs[0][tkq + 4][tn] = (double)rb1.x; Bs[0][tkq + 5][tn] = (double)rb1.y;
      Bs[0][tkq + 6][tn] = (double)rb1.z; Bs[0][tkq + 7][tn] = (double)rb1.w;
    }
  }
  __syncthreads();

  int buf = 0;
  for (int k0 = 0; k0 < K; k0 += 16) {
    const bool more = (k0 + 16) < K;
    if (more) {
      const int kn = k0 + 16;
      ra = *(const float4*)(A + (size_t)(m0 + am) * K + kn + akq);
      if (!BT) {
        const float* bp = B + (size_t)(kn + bk) * N + n0 + bn8;
        rb0 = *(const float4*)(bp); rb1 = *(const float4*)(bp + 4);
      } else {
        const float* bp = B + (size_t)(n0 + tn) * K + kn + tkq;
        rb0 = *(const float4*)(bp); rb1 = *(const float4*)(bp + 4);
      }
    }
#pragma unroll
    for (int ks = 0; ks < 4; ++ks) {
      const int kr = (ks << 2) + kl;
      double a0 = As[buf][kr][am0 + lm];
      double a1 = As[buf][kr][am0 + 16 + lm];
      double b0 = Bs[buf][kr][bn0 + lm];
      double b1 = Bs[buf][kr][bn0 + 16 + lm];
      double b2 = Bs[buf][kr][bn0 + 32 + lm];
      double b3 = Bs[buf][kr][bn0 + 48 + lm];
      c00 = __builtin_amdgcn_mfma_f64_16x16x4f64(a0, b0, c00, 0, 0, 0);
      c01 = __builtin_amdgcn_mfma_f64_16x16x4f64(a0, b1, c01, 0, 0, 0);
      c02 = __builtin_amdgcn_mfma_f64_16x16x4f64(a0, b2, c02, 0, 0, 0);
      c03 = __builtin_amdgcn_mfma_f64_16x16x4f64(a0, b3, c03, 0, 0, 0);
      c10 = __builtin_amdgcn_mfma_f64_16x16x4f64(a1, b0, c10, 0, 0, 0);
      c11 = __builtin_amdgcn_mfma_f64_16x16x4f64(a1, b1, c11, 0, 0, 0);
      c12 = __builtin_amdgcn_mfma_f64_16x16x4f64(a1, b2, c12, 0, 0, 0);
      c13 = __builtin_amdgcn_mfma_f64_16x16x4f64(a1, b3, c13, 0, 0, 0);
    }
    if (more) {
      const int nb = buf ^ 1;
      As[nb][akq + 0][am] = (double)ra.x; As[nb][akq + 1][am] = (double)ra.y;
      As[nb][akq + 2][am] = (double)ra.z; As[nb][akq + 3][am] = (double)ra.w;
      if (!BT) {
        Bs[nb][bk][bn8 + 0] = (double)rb0.x; Bs[nb][bk][bn8 + 1] = (double)rb0.y;
        Bs[nb][bk][bn8 + 2] = (double)rb0.z; Bs[nb][bk][bn8 + 3] = (double)rb0.w;
        Bs[nb][bk][bn8 + 4] = (double)rb1.x; Bs[nb][bk][bn8 + 5] = (double)rb1.y;
        Bs[nb][bk][bn8 + 6] = (double)rb1.z; Bs[nb][bk][bn8 + 7] = (double)rb1.w;
      } else {
        Bs[nb][tkq + 0][tn] = (double)rb0.x; Bs[nb][tkq + 1][tn] = (double)rb0.y;
        Bs[nb][tkq + 2][tn] = (double)rb0.z; Bs[nb][tkq + 3][tn] = (double)rb0.w;
        Bs[nb][tkq + 4][tn] = (double)rb1.x; Bs[nb][tkq + 5][tn] = (double)rb1.y;
        Bs[nb][tkq + 6][tn] = (double)rb1.z; Bs[nb][tkq + 7][tn] = (double)rb1.w;
      }
    }
    __syncthreads();
    buf ^= 1;
  }

#pragma unroll
  for (int i = 0; i < 4; ++i) {
    const size_t r0 = (size_t)(m0 + mr[i]) * N;
    const size_t r1 = r0 + (size_t)16 * N;
    const int c = n0 + nc[i];
    C[r0 + c +  0] = (float)(c00[i] * alpha);
    C[r0 + c + 16] = (float)(c01[i] * alpha);
    C[r0 + c + 32] = (float)(c02[i] * alpha);
    C[r0 + c + 48] = (float)(c03[i] * alpha);
    C[r1 + c +  0] = (float)(c10[i] * alpha);
    C[r1 + c + 16] = (float)(c11[i] * alpha);
    C[r1 + c + 32] = (float)(c12[i] * alpha);
    C[r1 + c + 48] = (float)(c13[i] * alpha);
  }
}

// ---------------------------------------------------------------------------
// bf16 hi-only SCREEN for S = (I @ P^T) * 2^-5. Values are used ONLY to pick
// top-NCAND candidates per row (exact rescore follows); noise ~2e-3 scaled
// vs rank-15->20 spacing ~0.07 -> candidate set safe by >20 sigma.
// 64x128 causal packed tile, BK=32, f32->bf16 at LDS staging, dbuf,
// 4 waves x (2x4) MFMA 16x16x32, layout probe as in r10's gemmbf.
// z = batch. C[m][n] = (I_z[m] . P_z[n]) * alpha  (hi-plane only)
// ---------------------------------------------------------------------------
__global__ void __launch_bounds__(256) gemmbfS(
    const float* __restrict__ I, const float* __restrict__ P,
    float* __restrict__ C, float alpha)
{
  int rem = blockIdx.x, bi = 0;
  while (rem >= (bi >> 1) + 1) { rem -= (bi >> 1) + 1; ++bi; }
  const int m0 = bi << 6, n0 = rem << 7;
  const int z = blockIdx.z;
  const float* A = I + (size_t)z * T_LEN * D_DIM;
  const float* B = P + (size_t)z * T_LEN * D_DIM;
  C += (size_t)z * T_LEN * T_LEN;
  const int N = T_LEN, K = D_DIM;

  const int tid = threadIdx.x;
  const int w = tid >> 6, lane = tid & 63;
  const int kg = lane >> 4, lm = lane & 15;
  const int am0 = (w & 1) << 5;
  const int bn0 = (w >> 1) << 6;

  __shared__ unsigned short As_h[2][64][40];
  __shared__ unsigned short Bs_h[2][128][40];

  bf16x8 ones;
#pragma unroll
  for (int e = 0; e < 8; ++e) ones[e] = (short)0x3F80;

  // layout probe (buf 0)
  for (int idx = tid; idx < 2048; idx += 256)
    As_h[0][idx >> 5][idx & 31] = f32_to_bf16_rne((float)(idx >> 5));
  for (int idx = tid; idx < 4096; idx += 256)
    Bs_h[0][idx >> 5][idx & 31] = f32_to_bf16_rne((float)(idx >> 5));
  __syncthreads();
  int mr[4], nc[4];
  {
    bf16x8 pa = *(const bf16x8*)&As_h[0][am0 + lm][kg << 3];
    bf16x8 pb = *(const bf16x8*)&Bs_h[0][bn0 + lm][kg << 3];
    f32x4v d1 = {0.f, 0.f, 0.f, 0.f}, d2 = {0.f, 0.f, 0.f, 0.f};
    d1 = __builtin_amdgcn_mfma_f32_16x16x32_bf16(pa, ones, d1, 0, 0, 0);
    d2 = __builtin_amdgcn_mfma_f32_16x16x32_bf16(ones, pb, d2, 0, 0, 0);
#pragma unroll
    for (int e = 0; e < 4; ++e) {
      mr[e] = ((int)d1[e]) >> 5;
      nc[e] = ((int)d2[e]) >> 5;
    }
  }
  __syncthreads();

  f32x4v c00 = {0,0,0,0}, c01 = {0,0,0,0}, c02 = {0,0,0,0}, c03 = {0,0,0,0};
  f32x4v c10 = {0,0,0,0}, c11 = {0,0,0,0}, c12 = {0,0,0,0}, c13 = {0,0,0,0};

  // staging ownership
  const int ar  = tid >> 2, ak8 = (tid & 3) << 3;              // A row, k-chunk
  const int bna = tid >> 2, bnb = 64 + (tid >> 2), bk8 = ak8;  // B rows (2 per thread)

  float4 fa0, fa1, fb0a, fb1a, fb0b, fb1b;

  // prologue: k0 = 0 -> buf 0
  {
    const float* ap = A + (size_t)(m0 + ar) * K + ak8;
    fa0 = *(const float4*)(ap); fa1 = *(const float4*)(ap + 4);
    const float* bpa = B + (size_t)(n0 + bna) * K + bk8;
    fb0a = *(const float4*)(bpa); fb1a = *(const float4*)(bpa + 4);
    const float* bpb = B + (size_t)(n0 + bnb) * K + bk8;
    fb0b = *(const float4*)(bpb); fb1b = *(const float4*)(bpb + 4);
  }
  {
    ushort4 h0, h1;
    h0.x = f32_to_bf16_rne(fa0.x); h0.y = f32_to_bf16_rne(fa0.y);
    h0.z = f32_to_bf16_rne(fa0.z); h0.w = f32_to_bf16_rne(fa0.w);
    h1.x = f32_to_bf16_rne(fa1.x); h1.y = f32_to_bf16_rne(fa1.y);
    h1.z = f32_to_bf16_rne(fa1.z); h1.w = f32_to_bf16_rne(fa1.w);
    *(ushort4*)&As_h[0][ar][ak8] = h0; *(ushort4*)&As_h[0][ar][ak8 + 4] = h1;
    h0.x = f32_to_bf16_rne(fb0a.x); h0.y = f32_to_bf16_rne(fb0a.y);
    h0.z = f32_to_bf16_rne(fb0a.z); h0.w = f32_to_bf16_rne(fb0a.w);
    h1.x = f32_to_bf16_rne(fb1a.x); h1.y = f32_to_bf16_rne(fb1a.y);
    h1.z = f32_to_bf16_rne(fb1a.z); h1.w = f32_to_bf16_rne(fb1a.w);
    *(ushort4*)&Bs_h[0][bna][bk8] = h0; *(ushort4*)&Bs_h[0][bna][bk8 + 4] = h1;
    h0.x = f32_to_bf16_rne(fb0b.x); h0.y = f32_to_bf16_rne(fb0b.y);
    h0.z = f32_to_bf16_rne(fb0b.z); h0.w = f32_to_bf16_rne(fb0b.w);
    h1.x = f32_to_bf16_rne(fb1b.x); h1.y = f32_to_bf16_rne(fb1b.y);
    h1.z = f32_to_bf16_rne(fb1b.z); h1.w = f32_to_bf16_rne(fb1b.w);
    *(ushort4*)&Bs_h[0][bnb][bk8] = h0; *(ushort4*)&Bs_h[0][bnb][bk8 + 4] = h1;
  }
  __syncthreads();

  int buf = 0;
  for (int k0 = 0; k0 < K; k0 += 32) {
    const bool more = (k0 + 32) < K;
    if (more) {
      const int kn = k0 + 32;
      const float* ap = A + (size_t)(m0 + ar) * K + kn + ak8;
      fa0 = *(const float4*)(ap); fa1 = *(const float4*)(ap + 4);
      const float* bpa = B + (size_t)(n0 + bna) * K + kn + bk8;
      fb0a = *(const float4*)(bpa); fb1a = *(const float4*)(bpa + 4);
      const float* bpb = B + (size_t)(n0 + bnb) * K + kn + bk8;
      fb0b = *(const float4*)(bpb); fb1b = *(const float4*)(bpb + 4);
    }
    {
      bf16x8 a0 = *(const bf16x8*)&As_h[buf][am0 + lm][kg << 3];
      bf16x8 a1 = *(const bf16x8*)&As_h[buf][am0 + 16 + lm][kg << 3];
      bf16x8 b0 = *(const bf16x8*)&Bs_h[buf][bn0 + lm][kg << 3];
      bf16x8 b1 = *(const bf16x8*)&Bs_h[buf][bn0 + 16 + lm][kg << 3];
      bf16x8 b2 = *(const bf16x8*)&Bs_h[buf][bn0 + 32 + lm][kg << 3];
      bf16x8 b3 = *(const bf16x8*)&Bs_h[buf][bn0 + 48 + lm][kg << 3];
      c00 = __builtin_amdgcn_mfma_f32_16x16x32_bf16(a0, b0, c00, 0, 0, 0);
      c01 = __builtin_amdgcn_mfma_f32_16x16x32_bf16(a0, b1, c01, 0, 0, 0);
      c02 = __builtin_amdgcn_mfma_f32_16x16x32_bf16(a0, b2, c02, 0, 0, 0);
      c03 = __builtin_amdgcn_mfma_f32_16x16x32_bf16(a0, b3, c03, 0, 0, 0);
      c10 = __builtin_amdgcn_mfma_f32_16x16x32_bf16(a1, b0, c10, 0, 0, 0);
      c11 = __builtin_amdgcn_mfma_f32_16x16x32_bf16(a1, b1, c11, 0, 0, 0);
      c12 = __builtin_amdgcn_mfma_f32_16x16x32_bf16(a1, b2, c12, 0, 0, 0);
      c13 = __builtin_amdgcn_mfma_f32_16x16x32_bf16(a1, b3, c13, 0, 0, 0);
    }
    if (more) {
      const int nb = buf ^ 1;
      ushort4 h0, h1;
      h0.x = f32_to_bf16_rne(fa0.x); h0.y = f32_to_bf16_rne(fa0.y);
      h0.z = f32_to_bf16_rne(fa0.z); h0.w = f32_to_bf16_rne(fa0.w);
      h1.x = f32_to_bf16_rne(fa1.x); h1.y = f32_to_bf16_rne(fa1.y);
      h1.z = f32_to_bf16_rne(fa1.z); h1.w = f32_to_bf16_rne(fa1.w);
      *(ushort4*)&As_h[nb][ar][ak8] = h0; *(ushort4*)&As_h[nb][ar][ak8 + 4] = h1;
      h0.x = f32_to_bf16_rne(fb0a.x); h0.y = f32_to_bf16_rne(fb0a.y);
      h0.z = f32_to_bf16_rne(fb0a.z); h0.w = f32_to_bf16_rne(fb0a.w);
      h1.x = f32_to_bf16_rne(fb1a.x); h1.y = f32_to_bf16_rne(fb1a.y);
      h1.z = f32_to_bf16_rne(fb1a.z); h1.w = f32_to_bf16_rne(fb1a.w);
      *(ushort4*)&Bs_h[nb][bna][bk8] = h0; *(ushort4*)&Bs_h[nb][bna][bk8 + 4] = h1;
      h0.x = f32_to_bf16_rne(fb0b.x); h0.y = f32_to_bf16_rne(fb0b.y);
      h0.z = f32_to_bf16_rne(fb0b.z); h0.w = f32_to_bf16_rne(fb0b.w);
      h1.x = f32_to_bf16_rne(fb1b.x); h1.y = f32_to_bf16_rne(fb1b.y);
      h1.z = f32_to_bf16_rne(fb1b.z); h1.w = f32_to_bf16_rne(fb1b.w);
      *(ushort4*)&Bs_h[nb][bnb][bk8] = h0; *(ushort4*)&Bs_h[nb][bnb][bk8 + 4] = h1;
    }
    __syncthreads();
    buf ^= 1;
  }

#pragma unroll
  for (int e = 0; e < 4; ++e) {
    const size_t r0 = (size_t)(m0 + mr[e]) * N;
    const size_t r1 = r0 + (size_t)16 * N;
    const int c = n0 + nc[e];
    C[r0 + c +  0] = c00[e] * alpha;
    C[r0 + c + 16] = c01[e] * alpha;
    C[r0 + c + 32] = c02[e] * alpha;
    C[r0 + c + 48] = c03[e] * alpha;
    C[r1 + c +  0] = c10[e] * alpha;
    C[r1 + c + 16] = c11[e] * alpha;
    C[r1 + c + 32] = c12[e] * alpha;
    C[r1 + c + 48] = c13[e] * alpha;
  }
}

// ---------------------------------------------------------------------------
// Top-NCAND screen candidates per causal row, both batches. -1 = invalid.
// ---------------------------------------------------------------------------
__global__ void __launch_bounds__(256) topk20(const float* __restrict__ Sb,
                                              int* __restrict__ cand)
{
  const int b = blockIdx.y;
  const float* S = Sb + (size_t)b * T_LEN * T_LEN;
  const int wave = threadIdx.x >> 6, lane = threadIdx.x & 63;
  const int t = blockIdx.x * 4 + wave;
  const float* rowp = S + (size_t)t * T_LEN;
  float v[32];
#pragma unroll
  for (int i = 0; i < 32; ++i) {
    int s = lane + (i << 6);
    v[i] = (s <= t) ? rowp[s] : -INFINITY;
  }
  float pv = INFINITY; int pidx = -1;
  int* outp = cand + ((size_t)b * T_LEN + t) * NCAND;
  for (int k = 0; k < NCAND; ++k) {
    float bv = -INFINITY; int bi = 0x7fffffff;
#pragma unroll
    for (int i = 0; i < 32; ++i) {
      int s = lane + (i << 6);
      float vv = v[i];
      bool elig = (vv < pv) || (vv == pv && s > pidx);
      if (elig && vv > bv) { bv = vv; bi = s; }
    }
#pragma unroll
    for (int o = 32; o >= 1; o >>= 1) {
      float ov = __shfl_xor(bv, o);
      int oi = __shfl_xor(bi, o);
      if (ov > bv || (ov == bv && oi < bi)) { bv = ov; bi = oi; }
    }
    pv = bv; pidx = bi;
    if (lane == 0) outp[k] = (bi == 0x7fffffff || bv == -INFINITY) ? -1 : bi;
  }
}

// ---------------------------------------------------------------------------
// Exact rescore: per row, f64 dot of I_t with each candidate P row, rounded
// to f32 AFTER the 2^-5 scale (replicates r3-r10's f32-compare semantics,
// tie -> lower index), select top-15 -> idx. f64 noise ~1e-15 << gaps ~1e-2.
// ---------------------------------------------------------------------------
__global__ void __launch_bounds__(256) rescore_kernel(
    const float* __restrict__ I, const float* __restrict__ P,
    const int* __restrict__ cand, int* __restrict__ idx)
{
  const int row = blockIdx.x;
  const int base = row & ~(T_LEN - 1);
  const int tid = threadIdx.x;
  const int w = tid >> 6, lane = tid & 63;

  __shared__ float valS[NCAND];
  __shared__ int   sidxS[NCAND];
  __shared__ int   candS[NCAND];

  if (tid < NCAND) candS[tid] = cand[(size_t)row * NCAND + tid];
  __syncthreads();

  // cache I row: 16 f64 per lane (coalesced 256B segments)
  double iv[16];
  const float* irow = I + (size_t)row * D_DIM;
#pragma unroll
  for (int j = 0; j < 16; ++j) iv[j] = (double)irow[lane + (j << 6)];

  for (int c = w; c < NCAND; c += 4) {
    int s = candS[c];
    double acc = 0.0;
    if (s >= 0) {
      const float* prow = P + ((size_t)base + s) * D_DIM;
#pragma unroll
      for (int j = 0; j < 16; ++j)
        acc = fma(iv[j], (double)prow[lane + (j << 6)], acc);
    }
#pragma unroll
    for (int o = 32; o >= 1; o >>= 1) acc += __shfl_xor(acc, o);
    if (lane == 0) {
      valS[c] = (s >= 0) ? (float)(acc * 0.03125) : -INFINITY;
      sidxS[c] = s;
    }
  }
  __syncthreads();
  if (tid == 0) {
    bool taken[NCAND];
#pragma unroll
    for (int c = 0; c < NCAND; ++c) taken[c] = false;
    int* outp = idx + (size_t)row * 16;
    for (int k = 0; k < KSEL; ++k) {
      float best = -INFINITY; int bidx = 0x7fffffff; int bc = -1;
      for (int c = 0; c < NCAND; ++c) {
        if (taken[c] || sidxS[c] < 0) continue;
        float v = valS[c];
        if (v > best || (v == best && sidxS[c] < bidx)) { best = v; bidx = sidxS[c]; bc = c; }
      }
      if (bc >= 0) { taken[bc] = true; outp[k] = bidx; }
      else outp[k] = 0;
    }
  }
}

// ---------------------------------------------------------------------------
// Split f32 array into bf16 hi/lo planes. (r10, unchanged.)
// ---------------------------------------------------------------------------
__global__ void __launch_bounds__(256) split_bf16(const float* __restrict__ X,
                                                  unsigned short* __restrict__ H,
                                                  unsigned short* __restrict__ L)
{
  const int i = (blockIdx.x * 256 + threadIdx.x) * 4;
  float4 v = *(const float4*)(X + i);
  ushort4 h, l;
  h.x = f32_to_bf16_rne(v.x); l.x = f32_to_bf16_rne(v.x - bf16_to_f32(h.x));
  h.y = f32_to_bf16_rne(v.y); l.y = f32_to_bf16_rne(v.y - bf16_to_f32(h.y));
  h.z = f32_to_bf16_rne(v.z); l.z = f32_to_bf16_rne(v.z - bf16_to_f32(h.z));
  h.w = f32_to_bf16_rne(v.w); l.w = f32_to_bf16_rne(v.w - bf16_to_f32(h.w));
  *(ushort4*)(H + i) = h;
  *(ushort4*)(L + i) = l;
}

// ---------------------------------------------------------------------------
// Wo (K x N) -> transposed bf16 hi/lo planes (N x K). (r10, unchanged.)
// ---------------------------------------------------------------------------
__global__ void __launch_bounds__(256) woconvT(const float* __restrict__ Wo,
                                               unsigned short* __restrict__ HT,
                                               unsigned short* __restrict__ LT)
{
  __shared__ float tile[64][65];
  const int k0 = blockIdx.y << 6, n0 = blockIdx.x << 6;
  const int tid = threadIdx.x;
  for (int idx = tid; idx < 4096; idx += 256) {
    int r = idx >> 6, c = idx & 63;
    tile[r][c] = Wo[(size_t)(k0 + r) * D_DIM + n0 + c];
  }
  __syncthreads();
  for (int idx = tid; idx < 4096; idx += 256) {
    int n = idx >> 6, k = idx & 63;
    float v = tile[k][n];
    unsigned short h = f32_to_bf16_rne(v);
    HT[(size_t)(n0 + n) * D_DIM + k0 + k] = h;
    LT[(size_t)(n0 + n) * D_DIM + k0 + k] = f32_to_bf16_rne(v - bf16_to_f32(h));
  }
}

// ---------------------------------------------------------------------------
// Split-bf16 MFMA GEMM for out = V @ Wo. (r10, unchanged.)
// ---------------------------------------------------------------------------
__global__ void __launch_bounds__(256) gemmbf(
    const unsigned short* __restrict__ Ah, const unsigned short* __restrict__ Al,
    const unsigned short* __restrict__ BhT, const unsigned short* __restrict__ BlT,
    float* __restrict__ C, int N, int K)
{
  const int m0 = blockIdx.y << 6, n0 = blockIdx.x << 7;
  const int tid = threadIdx.x;
  const int w = tid >> 6, lane = tid & 63;
  const int kg = lane >> 4, lm = lane & 15;
  const int am0 = (w & 1) << 5;
  const int bn0 = (w >> 1) << 6;

  __shared__ unsigned short As_h[2][64][40],  As_l[2][64][40];
  __shared__ unsigned short Bs_h[2][128][40], Bs_l[2][128][40];

  bf16x8 ones;
#pragma unroll
  for (int e = 0; e < 8; ++e) ones[e] = (short)0x3F80;

  for (int idx = tid; idx < 2048; idx += 256)
    As_h[0][idx >> 5][idx & 31] = f32_to_bf16_rne((float)(idx >> 5));
  for (int idx = tid; idx < 4096; idx += 256)
    Bs_h[0][idx >> 5][idx & 31] = f32_to_bf16_rne((float)(idx >> 5));
  __syncthreads();
  int mr[4], nc[4];
  {
    bf16x8 pa = *(const bf16x8*)&As_h[0][am0 + lm][kg << 3];
    bf16x8 pb = *(const bf16x8*)&Bs_h[0][bn0 + lm][kg << 3];
    f32x4v d1 = {0.f, 0.f, 0.f, 0.f}, d2 = {0.f, 0.f, 0.f, 0.f};
    d1 = __builtin_amdgcn_mfma_f32_16x16x32_bf16(pa, ones, d1, 0, 0, 0);
    d2 = __builtin_amdgcn_mfma_f32_16x16x32_bf16(ones, pb, d2, 0, 0, 0);
#pragma unroll
    for (int e = 0; e < 4; ++e) {
      mr[e] = ((int)d1[e]) >> 5;
      nc[e] = ((int)d2[e]) >> 5;
    }
  }
  __syncthreads();

  f32x4v c00 = {0,0,0,0}, c01 = {0,0,0,0}, c02 = {0,0,0,0}, c03 = {0,0,0,0};
  f32x4v c10 = {0,0,0,0}, c11 = {0,0,0,0}, c12 = {0,0,0,0}, c13 = {0,0,0,0};

  const int ar  = tid >> 2, ak8 = (tid & 3) << 3;
  const int bna = tid >> 2, bnb = 64 + (tid >> 2), bk8 = (tid & 3) << 3;

  bf16x8 rah, ral, rbh0, rbl0, rbh1, rbl1;

  rah  = *(const bf16x8*)(Ah  + (size_t)(m0 + ar) * K + ak8);
  ral  = *(const bf16x8*)(Al  + (size_t)(m0 + ar) * K + ak8);
  rbh0 = *(const bf16x8*)(BhT + (size_t)(n0 + bna) * K + bk8);
  rbl0 = *(const bf16x8*)(BlT + (size_t)(n0 + bna) * K + bk8);
  rbh1 = *(const bf16x8*)(BhT + (size_t)(n0 + bnb) * K + bk8);
  rbl1 = *(const bf16x8*)(BlT + (size_t)(n0 + bnb) * K + bk8);
  *(bf16x8*)&As_h[0][ar][ak8]  = rah;
  *(bf16x8*)&As_l[0][ar][ak8]  = ral;
  *(bf16x8*)&Bs_h[0][bna][bk8] = rbh0;
  *(bf16x8*)&Bs_l[0][bna][bk8] = rbl0;
  *(bf16x8*)&Bs_h[0][bnb][bk8] = rbh1;
  *(bf16x8*)&Bs_l[0][bnb][bk8] = rbl1;
  __syncthreads();

  int buf = 0;
  for (int k0 = 0; k0 < K; k0 += 32) {
    const bool more = (k0 + 32) < K;
    if (more) {
      const int kn = k0 + 32;
      rah  = *(const bf16x8*)(Ah  + (size_t)(m0 + ar) * K + kn + ak8);
      ral  = *(const bf16x8*)(Al  + (size_t)(m0 + ar) * K + kn + ak8);
      rbh0 = *(const bf16x8*)(BhT + (size_t)(n0 + bna) * K + kn + bk8);
      rbl0 = *(const bf16x8*)(BlT + (size_t)(n0 + bna) * K + kn + bk8);
      rbh1 = *(const bf16x8*)(BhT + (size_t)(n0 + bnb) * K + kn + bk8);
      rbl1 = *(const bf16x8*)(BlT + (size_t)(n0 + bnb) * K + kn + bk8);
    }
    {
      bf16x8 ah0 = *(const bf16x8*)&As_h[buf][am0 + lm][kg << 3];
      bf16x8 ah1 = *(const bf16x8*)&As_h[buf][am0 + 16 + lm][kg << 3];
      bf16x8 al0 = *(const bf16x8*)&As_l[buf][am0 + lm][kg << 3];
      bf16x8 al1 = *(const bf16x8*)&As_l[buf][am0 + 16 + lm][kg << 3];
      bf16x8 bh0 = *(const bf16x8*)&Bs_h[buf][bn0 + lm][kg << 3];
      bf16x8 bh1 = *(const bf16x8*)&Bs_h[buf][bn0 + 16 + lm][kg << 3];
      bf16x8 bh2 = *(const bf16x8*)&Bs_h[buf][bn0 + 32 + lm][kg << 3];
      bf16x8 bh3 = *(const bf16x8*)&Bs_h[buf][bn0 + 48 + lm][kg << 3];
      bf16x8 bl0 = *(const bf16x8*)&Bs_l[buf][bn0 + lm][kg << 3];
      bf16x8 bl1 = *(const bf16x8*)&Bs_l[buf][bn0 + 16 + lm][kg << 3];
      bf16x8 bl2 = *(const bf16x8*)&Bs_l[buf][bn0 + 32 + lm][kg << 3];
      bf16x8 bl3 = *(const bf16x8*)&Bs_l[buf][bn0 + 48 + lm][kg << 3];

      c00 = __builtin_amdgcn_mfma_f32_16x16x32_bf16(ah0, bh0, c00, 0, 0, 0);
      c01 = __builtin_amdgcn_mfma_f32_16x16x32_bf16(ah0, bh1, c01, 0, 0, 0);
      c02 = __builtin_amdgcn_mfma_f32_16x16x32_bf16(ah0, bh2, c02, 0, 0, 0);
      c03 = __builtin_amdgcn_mfma_f32_16x16x32_bf16(ah0, bh3, c03, 0, 0, 0);
      c10 = __builtin_amdgcn_mfma_f32_16x16x32_bf16(ah1, bh0, c10, 0, 0, 0);
      c11 = __builtin_amdgcn_mfma_f32_16x16x32_bf16(ah1, bh1, c11, 0, 0, 0);
      c12 = __builtin_amdgcn_mfma_f32_16x16x32_bf16(ah1, bh2, c12, 0, 0, 0);
      c13 = __builtin_amdgcn_mfma_f32_16x16x32_bf16(ah1, bh3, c13, 0, 0, 0);

      c00 = __builtin_amdgcn_mfma_f32_16x16x32_bf16(ah0, bl0, c00, 0, 0, 0);
      c01 = __builtin_amdgcn_mfma_f32_16x16x32_bf16(ah0, bl1, c01, 0, 0, 0);
      c02 = __builtin_amdgcn_mfma_f32_16x16x32_bf16(ah0, bl2, c02, 0, 0, 0);
      c03 = __builtin_amdgcn_mfma_f32_16x16x32_bf16(ah0, bl3, c03, 0, 0, 0);
      c10 = __builtin_amdgcn_mfma_f32_16x16x32_bf16(ah1, bl0, c10, 0, 0, 0);
      c11 = __builtin_amdgcn_mfma_f32_16x16x32_bf16(ah1, bl1, c11, 0, 0, 0);
      c12 = __builtin_amdgcn_mfma_f32_16x16x32_bf16(ah1, bl2, c12, 0, 0, 0);
      c13 = __builtin_amdgcn_mfma_f32_16x16x32_bf16(ah1, bl3, c13, 0, 0, 0);

      c00 = __builtin_amdgcn_mfma_f32_16x16x32_bf16(al0, bh0, c00, 0, 0, 0);
      c01 = __builtin_amdgcn_mfma_f32_16x16x32_bf16(al0, bh1, c01, 0, 0, 0);
      c02 = __builtin_amdgcn_mfma_f32_16x16x32_bf16(al0, bh2, c02, 0, 0, 0);
      c03 = __builtin_amdgcn_mfma_f32_16x16x32_bf16(al0, bh3, c03, 0, 0, 0);
      c10 = __builtin_amdgcn_mfma_f32_16x16x32_bf16(al1, bh0, c10, 0, 0, 0);
      c11 = __builtin_amdgcn_mfma_f32_16x16x32_bf16(al1, bh1, c11, 0, 0, 0);
      c12 = __builtin_amdgcn_mfma_f32_16x16x32_bf16(al1, bh2, c12, 0, 0, 0);
      c13 = __builtin_amdgcn_mfma_f32_16x16x32_bf16(al1, bh3, c13, 0, 0, 0);
    }
    if (more) {
      const int nb = buf ^ 1;
      *(bf16x8*)&As_h[nb][ar][ak8]  = rah;
      *(bf16x8*)&As_l[nb][ar][ak8]  = ral;
      *(bf16x8*)&Bs_h[nb][bna][bk8] = rbh0;
      *(bf16x8*)&Bs_l[nb][bna][bk8] = rbl0;
      *(bf16x8*)&Bs_h[nb][bnb][bk8] = rbh1;
      *(bf16x8*)&Bs_l[nb][bnb][bk8] = rbl1;
    }
    __syncthreads();
    buf ^= 1;
  }

#pragma unroll
  for (int e = 0; e < 4; ++e) {
    const size_t r0 = (size_t)(m0 + mr[e]) * N;
    const size_t r1 = r0 + (size_t)16 * N;
    const int c = n0 + nc[e];
    C[r0 + c +  0] = c00[e];
    C[r0 + c + 16] = c01[e];
    C[r0 + c + 32] = c02[e];
    C[r0 + c + 48] = c03[e];
    C[r1 + c +  0] = c10[e];
    C[r1 + c + 16] = c11[e];
    C[r1 + c + 32] = c12[e];
    C[r1 + c + 48] = c13[e];
  }
}

// ---------------------------------------------------------------------------
// Trig table: EXACT reference f32 bits. DO NOT change — selection-critical.
// ---------------------------------------------------------------------------
__global__ void __launch_bounds__(256) trig_table_kernel(float2* __restrict__ tab)
{
  const int t = blockIdx.x;
  for (int j = threadIdx.x; j < 512; j += 256) {
    double e = (double)j * (1.0 / 512.0);
    float pf = (float)pow(10000.0, e);
    float invf = 1.0f / pf;
    float angf = (float)t * invf;
    double s64, c64;
    sincos((double)angf, &s64, &c64);
    tab[(size_t)t * 512 + j] = make_float2((float)c64, (float)s64);
  }
}

// ---------------------------------------------------------------------------
// RoPE in place + row L2 norms. DO NOT change — selection-critical.
// ---------------------------------------------------------------------------
__global__ void __launch_bounds__(256) rope_norm_kernel(float* __restrict__ bI,
                                                        float* __restrict__ bP,
                                                        const float2* __restrict__ tab,
                                                        float* __restrict__ nI,
                                                        float* __restrict__ nP)
{
  const int row = blockIdx.x;
  const int t = row & (T_LEN - 1);
  const int tid = threadIdx.x;
  __shared__ double redI[4], redP[4];
  double ssI = 0.0, ssP = 0.0;
  const size_t off = (size_t)row * D_DIM;
  for (int j = tid; j < 512; j += 256) {
    float2 cs = tab[(size_t)t * 512 + j];
    float c = cs.x, s = cs.y;

    float a1 = bI[off + j], a2 = bI[off + 512 + j];
    float o1 = __fsub_rn(__fmul_rn(a1, c), __fmul_rn(a2, s));
    float o2 = __fadd_rn(__fmul_rn(a1, s), __fmul_rn(a2, c));
    bI[off + j] = o1; bI[off + 512 + j] = o2;
    ssI += (double)o1 * o1 + (double)o2 * o2;

    float p1 = bP[off + j], p2 = bP[off + 512 + j];
    float q1 = __fsub_rn(__fmul_rn(p1, c), __fmul_rn(p2, s));
    float q2 = __fadd_rn(__fmul_rn(p1, s), __fmul_rn(p2, c));
    bP[off + j] = q1; bP[off + 512 + j] = q2;
    ssP += (double)q1 * q1 + (double)q2 * q2;
  }
#pragma unroll
  for (int o = 32; o >= 1; o >>= 1) { ssI += __shfl_xor(ssI, o); ssP += __shfl_xor(ssP, o); }
  if ((tid & 63) == 0) { redI[tid >> 6] = ssI; redP[tid >> 6] = ssP; }
  __syncthreads();
  if (tid == 0) {
    nI[row] = fmaxf((float)sqrt(redI[0] + redI[1] + redI[2] + redI[3]), 1e-12f);
    nP[row] = fmaxf((float)sqrt(redP[0] + redP[1] + redP[2] + redP[3]), 1e-12f);
  }
}

// ---------------------------------------------------------------------------
// palette (D x 256) -> palT (256 x D)
// ---------------------------------------------------------------------------
__global__ void transpose_pal(const float* __restrict__ pal, float* __restrict__ palT)
{
  int c = blockIdx.x;
  int d = blockIdx.y * 256 + threadIdx.x;
  palT[(size_t)c * D_DIM + d] = pal[(size_t)d * 256 + c];
}

// ---------------------------------------------------------------------------
// Per-(b,t): gather + normalized gram + rel features + MLP + heads + softmax
// + bilinear palette blend -> V[b,t,:]. (unchanged)
// ---------------------------------------------------------------------------
__global__ void __launch_bounds__(256) relmlp_kernel(
    const float* __restrict__ I, const float* __restrict__ P,
    const float* __restrict__ nI, const float* __restrict__ nP,
    const int* __restrict__ topk,
    const float* __restrict__ W1, const float* __restrict__ b1,
    const float* __restrict__ W2, const float* __restrict__ b2,
    const float* __restrict__ Wc, const float* __restrict__ bc,
    const float* __restrict__ Wm, const float* __restrict__ bm,
    const float* __restrict__ palT, float* __restrict__ V)
{
  const int row = blockIdx.x;
  const int t = row & (T_LEN - 1);
  const int base = row & ~(T_LEN - 1);
  const int nk = (t + 1 < KSEL) ? (t + 1) : KSEL;
  const int tid = threadIdx.x;

  __shared__ float vecS[16][516];
  __shared__ float gS[16][16];
  __shared__ float relS[KSEL][17];
  __shared__ float h1S[KSEL][HIDN];
  __shared__ float h2S[KSEL][HIDN];
  __shared__ float nrmS[16];
  __shared__ int   sidxS[16];
  __shared__ float mixS[KSEL], wS[KSEL], zxS[KSEL], zyS[KSEL];
  __shared__ float coefS[4 * KSEL];
  __shared__ int   cellS[4 * KSEL];

  if (tid < 16) {
    int s = t;
    if (tid >= 1) s = (tid <= nk) ? topk[(size_t)row * 16 + (tid - 1)] : 0;
    sidxS[tid] = s;
    nrmS[tid] = (tid == 0) ? nI[row] : nP[base + s];
  }
  __syncthreads();

  const int r = tid >> 4, c0 = tid & 15;
  const float* srcrow = (r == 0) ? (I + (size_t)row * D_DIM)
                                 : (P + ((size_t)base + sidxS[r]) * D_DIM);

  int pi = 0, pj = 0;
  {
    int p = tid;
    if (p < 136) {
      int i = 0;
      while (p >= 16 - i) { p -= 16 - i; ++i; }
      pi = i; pj = i + p;
    }
  }
  const bool pairOn = (tid < 136) && (pi <= nk) && (pj <= nk);
  float4 acc4 = make_float4(0.f, 0.f, 0.f, 0.f);

  for (int half = 0; half < 2; ++half) {
    if (half) __syncthreads();
    if (r <= nk) {
#pragma unroll
      for (int rep = 0; rep < 8; ++rep) {
        int q = c0 + 16 * rep;
        float4 v4 = *(const float4*)(srcrow + half * 512 + (q << 2));
        *(float4*)&vecS[r][q << 2] = v4;
      }
    }
    __syncthreads();
    if (pairOn) {
      const float4* va = (const float4*)&vecS[pi][0];
      const float4* vb = (const float4*)&vecS[pj][0];
#pragma unroll 4
      for (int q = 0; q < 128; ++q) {
        float4 a4 = va[q], b4 = vb[q];
        acc4.x = fmaf(a4.x, b4.x, acc4.x);
        acc4.y = fmaf(a4.y, b4.y, acc4.y);
        acc4.z = fmaf(a4.z, b4.z, acc4.z);
        acc4.w = fmaf(a4.w, b4.w, acc4.w);
      }
    }
  }
  if (tid < 136) {
    float g = 0.f;
    if (pairOn) {
      float acc = (acc4.x + acc4.y) + (acc4.z + acc4.w);
      g = acc / (nrmS[pi] * nrmS[pj]);
      g = fminf(fmaxf(g, -1.f), 1.f);
    }
    gS[pi][pj] = g;
    gS[pj][pi] = g;
  }
  __syncthreads();

  if (tid < KSEL * 17) {
    int k = tid / 17, f = tid % 17;
    float v = 0.f;
    if (k < nk) {
      if (f < KSEL)        v = (f < nk) ? gS[k + 1][f + 1] : 0.f;
      else if (f == KSEL)  v = gS[0][k + 1];
      else                 v = (float)(t - sidxS[k + 1]) * (1.0f / (float)T_LEN);
    }
    relS[k][f] = v;
  }
  __syncthreads();

  for (int o = tid; o < KSEL * HIDN; o += 256) {
    int k = o >> 6, m = o & 63;
    float a = b1[m];
#pragma unroll
    for (int f = 0; f < 17; ++f) a = fmaf(relS[k][f], W1[f * HIDN + m], a);
    h1S[k][m] = geluf(a);
  }
  __syncthreads();
  for (int o = tid; o < KSEL * HIDN; o += 256) {
    int k = o >> 6, m = o & 63;
    float a = b2[m];
#pragma unroll 8
    for (int n = 0; n < HIDN; ++n) a = fmaf(h1S[k][n], W2[n * HIDN + m], a);
    h2S[k][m] = geluf(a);
  }
  __syncthreads();
  if (tid < KSEL) {
    float a0 = 0.f, a1 = 0.f, am = 0.f;
#pragma unroll 8
    for (int n = 0; n < HIDN; ++n) {
      float h = h2S[tid][n];
      a0 = fmaf(h, Wc[n * 2 + 0], a0);
      a1 = fmaf(h, Wc[n * 2 + 1], a1);
      am = fmaf(h, Wm[n], am);
    }
    zxS[tid] = tanhf(a0 + bc[0]);
    zyS[tid] = tanhf(a1 + bc[1]);
    mixS[tid] = am + bm[0];
  }
  __syncthreads();
  if (tid == 0) {
    float mx = -INFINITY;
    for (int k = 0; k < nk; ++k) mx = fmaxf(mx, mixS[k]);
    float ssum = 0.f;
    for (int k = 0; k < nk; ++k) { float e = expf(mixS[k] - mx); wS[k] = e; ssum += e; }
    float inv = 1.f / ssum;
    for (int k = 0; k < nk; ++k) wS[k] *= inv;
  }
  __syncthreads();
  if (tid < KSEL) {
    int k = tid;
    if (k < nk) {
      float w = wS[k];
      float fx = fminf(fmaxf((zxS[k] + 1.f) * 0.5f * 15.f, 0.f), 15.f);
      float fy = fminf(fmaxf((zyS[k] + 1.f) * 0.5f * 15.f, 0.f), 15.f);
      int x0 = (int)floorf(fx); int x1i = (x0 + 1 < 15) ? x0 + 1 : 15;
      int y0 = (int)floorf(fy); int y1i = (y0 + 1 < 15) ? y0 + 1 : 15;
      float wx = fx - (float)x0, wy = fy - (float)y0;
      cellS[k * 4 + 0] = y0 * 16 + x0;   coefS[k * 4 + 0] = w * (1.f - wy) * (1.f - wx);
      cellS[k * 4 + 1] = y0 * 16 + x1i;  coefS[k * 4 + 1] = w * (1.f - wy) * wx;
      cellS[k * 4 + 2] = y1i * 16 + x0;  coefS[k * 4 + 2] = w * wy * (1.f - wx);
      cellS[k * 4 + 3] = y1i * 16 + x1i; coefS[k * 4 + 3] = w * wy * wx;
    } else {
      cellS[k * 4 + 0] = cellS[k * 4 + 1] = cellS[k * 4 + 2] = cellS[k * 4 + 3] = 0;
      coefS[k * 4 + 0] = coefS[k * 4 + 1] = coefS[k * 4 + 2] = coefS[k * 4 + 3] = 0.f;
    }
  }
  __syncthreads();
  const int nj = 4 * nk;
  for (int d = tid; d < D_DIM; d += 256) {
    float a = 0.f;
    for (int j = 0; j < nj; ++j)
      a = fmaf(coefS[j], palT[(size_t)cellS[j] * D_DIM + d], a);
    V[(size_t)row * D_DIM + d] = a;
  }
}

// ---------------------------------------------------------------------------
// Host launcher.
// ---------------------------------------------------------------------------
extern "C" void kernel_launch(void* const* d_in, const int* in_sizes, int n_in,
                              void* d_out, int out_size, void* d_ws, size_t ws_size,
                              hipStream_t stream)
{
  (void)in_sizes; (void)n_in; (void)out_size; (void)ws_size;
  const float* x   = (const float*)d_in[0];
  const float* Wi  = (const float*)d_in[1];
  const float* Wp  = (const float*)d_in[2];
  const float* pal = (const float*)d_in[3];
  const float* W1  = (const float*)d_in[4];
  const float* b1  = (const float*)d_in[5];
  const float* W2  = (const float*)d_in[6];
  const float* b2  = (const float*)d_in[7];
  const float* Wc  = (const float*)d_in[8];
  const float* bc  = (const float*)d_in[9];
  const float* Wm  = (const float*)d_in[10];
  const float* bm  = (const float*)d_in[11];
  const float* Wo  = (const float*)d_in[12];
  float* out = (float*)d_out;

  float* w = (float*)d_ws;
  float* palT = w;  w += (size_t)256 * D_DIM;
  float* I    = w;  w += (size_t)BATCH * T_LEN * D_DIM;
  float* P    = w;  w += (size_t)BATCH * T_LEN * D_DIM;
  float* Sb   = w;  w += (size_t)BATCH * T_LEN * T_LEN;
  float* nIb  = w;  w += (size_t)BATCH * T_LEN;
  float* nPb  = w;  w += (size_t)BATCH * T_LEN;
  int*   idx  = (int*)w;  w += (size_t)BATCH * T_LEN * 16 / 1;   // 16 ints/row
  int*   cand = (int*)w;                                          // NCAND ints/row

  float2* tab = (float2*)Sb;                     // pre-S
  float*  Vb  = Sb;                              // post-topk, first 16MB
  unsigned short* Vh = (unsigned short*)(Sb + (size_t)4 * 1024 * 1024);
  unsigned short* Vl = Vh + (size_t)4 * 1024 * 1024;
  unsigned short* WohT = (unsigned short*)P;     // P dead after relmlp
  unsigned short* WolT = WohT + (size_t)D_DIM * D_DIM;

  const int MROWS = BATCH * T_LEN;  // 4096

  trig_table_kernel<<<T_LEN, 256, 0, stream>>>(tab);
  transpose_pal<<<dim3(256, 4), 256, 0, stream>>>(pal, palT);

  // I = x@Wi (z=0), P = x@Wp (z=1): f64 MFMA (selection-critical values).
  gemm64q<false, false><<<dim3(D_DIM / 128, MROWS / 64, 2), 256, 0, stream>>>(
      x, Wi, Wp, I, D_DIM, D_DIM,
      0L, 0L, (long)MROWS * D_DIM, 1.0);

  rope_norm_kernel<<<MROWS, 256, 0, stream>>>(I, P, tab, nIb, nPb);

  // S screen: bf16 hi-only MFMA (values only gate CANDIDATES).
  gemmbfS<<<dim3(272, 1, 2), 256, 0, stream>>>(I, P, Sb, 0.03125f);

  // top-NCAND candidates per row, then exact f64 rescore -> top-15 indices.
  topk20<<<dim3(T_LEN / 4, BATCH), 256, 0, stream>>>(Sb, cand);
  rescore_kernel<<<MROWS, 256, 0, stream>>>(I, P, cand, idx);

  relmlp_kernel<<<MROWS, 256, 0, stream>>>(I, P, nIb, nPb, idx,
                                           W1, b1, W2, b2, Wc, bc, Wm, bm,
                                           palT, Vb);

  // V @ Wo via split-bf16 MFMA (r10)
  split_bf16<<<(MROWS * D_DIM) / (256 * 4), 256, 0, stream>>>(Vb, Vh, Vl);
  woconvT<<<dim3(D_DIM / 64, D_DIM / 64), 256, 0, stream>>>(Wo, WohT, WolT);
  gemmbf<<<dim3(D_DIM / 128, MROWS / 64), 256, 0, stream>>>(
      Vh, Vl, WohT, WolT, out, D_DIM, D_DIM);
}